// Round 13
// baseline (1752.213 us; speedup 1.0000x reference)
//
#include <hip/hip_runtime.h>
#include <math.h>

// Problem constants (match reference)
#define NN 200000
#define EE 300000
#define BB 64
#define INV_SQRT_D 0.17677669529663687f

// ---- workspace layout in 4-byte words. Total ≈ 58.38M words = 233.5 MB.
// ws budget is ~256MB-class (252 passed, 329 faulted) -> stay <= 252 MB.
#define OFF_HB   ((size_t)0)                    // [N][64] uint (bf16x2) node features
#define OFF_P0   ((size_t)12800000)             // [N][64] uint: q, then vt_0, then vt_2
#define OFF_P1   ((size_t)25600000)             // [N][64] uint: kt_r, then vt_1
#define OFF_AS   ((size_t)38400000)             // [N][64] uint: As accumulator (bf16)
#define OFF_S    ((size_t)51200000)             // [3][E][4] f32 scores -> exp (CSR order)
#define OFF_RP   ((size_t)54800000)             // [3][N+1] int rowptr (padded 600016)
#define OFF_CSRC ((size_t)55400016)             // [3][E] int src per CSR position
#define OFF_CDST ((size_t)56300016)             // [3][E] int dst per CSR position
#define OFF_WF   ((size_t)57200016)             // 14 x [128][128] f32 folded weights
#define OFF_BF   ((size_t)57429392)             // 14 x [128] f32 folded bias
#define OFF_BS   ((size_t)57431184)             // scan block sums 3*128 int
#define OFF_POOL ((size_t)57431568)             // psum [B][256] + pcnt [B][2] (16512)
#define OFF_WT   ((size_t)57448080)             // 16 x [128][64] uint packed W^T
#define OFF_IZ   ((size_t)57579152)             // [N][4] f32 softmax 1/Z

#define SCAN_L   (NN + 1)
#define SCAN_E   8
#define SCAN_EPB (256 * SCAN_E)                          // 2048
#define SCAN_NB  ((SCAN_L + SCAN_EPB - 1) / SCAN_EPB)    // 98

typedef __attribute__((ext_vector_type(8))) short bf16x8;
typedef __attribute__((ext_vector_type(4))) float f32x4;

__device__ __forceinline__ float gelu_exact(float v) {
    return 0.5f * v * (1.0f + erff(v * 0.70710678118654752f));
}
__device__ __forceinline__ float bflo(unsigned u) { return __uint_as_float(u << 16); }
__device__ __forceinline__ float bfhi(unsigned u) { return __uint_as_float(u & 0xffff0000u); }
__device__ __forceinline__ unsigned bfpack(float a, float b) {
    unsigned ua = __float_as_uint(a); ua += 0x7fffu + ((ua >> 16) & 1u);
    unsigned ub = __float_as_uint(b); ub += 0x7fffu + ((ub >> 16) & 1u);
    return (ua >> 16) | (ub & 0xffff0000u);
}

// ---- fold weights. 14 slots: per layer l: [l*7+0]=q copy, [l*7+1+r]=k@Wk_rel[r],
//      [l*7+4+r]=v@Wv_rel[r].  kqv split order is k|q|v (cols 0/128/256).
__global__ __launch_bounds__(256) void fold_weights(
    const float* __restrict__ Wkqv, const float* __restrict__ bkqv,
    const float* __restrict__ Wk_rel, const float* __restrict__ Wv_rel,
    float* __restrict__ Wf, float* __restrict__ bf)
{
    __shared__ float Wr[4096];
    const int b = blockIdx.x, t = threadIdx.x;
    const int l = b / 7, s = b % 7;
    const float* Wq = Wkqv + (size_t)l * 49152;   // [128][384]
    if (s == 0) {
        for (int i = t; i < 16384; i += 256) {
            int kk = i >> 7, c = i & 127;
            Wf[(size_t)b * 16384 + i] = Wq[kk * 384 + 128 + c];
        }
        if (t < 128) bf[b * 128 + t] = bkqv[l * 384 + 128 + t];
    } else {
        const int side = (s - 1) / 3, r = (s - 1) % 3;
        const int off = side ? 256 : 0;
        const float* Wrel = (side ? Wv_rel : Wk_rel) + (size_t)(l * 3 + r) * 4096;
        for (int i = t; i < 4096; i += 256) Wr[i] = Wrel[i];
        __syncthreads();
        for (int i = t; i < 16384; i += 256) {
            int kk = i >> 7, c = i & 127, hh = c >> 5, f = c & 31;
            const float* wrow = Wq + kk * 384 + off + hh * 32;
            const float* wr = Wr + hh * 1024 + f;
            float sum = 0.f;
#pragma unroll
            for (int d = 0; d < 32; ++d) sum += wrow[d] * wr[d * 32];
            Wf[(size_t)b * 16384 + i] = sum;
        }
        if (t < 128) {
            int hh = t >> 5, f = t & 31;
            float sum = 0.f;
#pragma unroll
            for (int d = 0; d < 32; ++d)
                sum += bkqv[l * 384 + off + hh * 32 + d] * Wr[hh * 1024 + d * 32 + f];
            bf[b * 128 + t] = sum;
        }
    }
}

// ---- pack W -> bf16x2-packed W^T: WT[slot][c][w] = (W[2w][c], W[2w+1][c]) ----
__global__ __launch_bounds__(256) void pack_wt(
    const float* __restrict__ W, unsigned* __restrict__ WT)
{
    const int slot = blockIdx.x, t = threadIdx.x;
    const float* Ws = W + (size_t)slot * 16384;
    unsigned* WTs = WT + (size_t)slot * 8192;
    for (int i = t; i < 8192; i += 256) {
        int c = i >> 6, w = i & 63;
        WTs[i] = bfpack(Ws[(size_t)(2 * w) * 128 + c], Ws[(size_t)(2 * w + 1) * 128 + c]);
    }
}

// ---------------- input projection: h_bf = bf16([emb[ast], x] @ Win + bin) ----------------
__global__ __launch_bounds__(256) void input_proj(
    const float* __restrict__ x, const int* __restrict__ ast,
    const float* __restrict__ emb, const float* __restrict__ Win,
    const float* __restrict__ bin_, unsigned* __restrict__ h_bf)
{
    __shared__ float Ws[69 * 128];
    __shared__ float As[16 * 70];
    const int t = threadIdx.x;
    const int n0 = blockIdx.x * 16;
    for (int i = t; i < 69 * 128; i += 256) Ws[i] = Win[i];
    for (int i = t; i < 16 * 69; i += 256) {
        int nl = i / 69, kk = i - nl * 69;
        int n = n0 + nl;
        float v = (kk < 64) ? emb[ast[n] * 64 + kk] : x[n * 5 + (kk - 64)];
        As[nl * 70 + kk] = v;
    }
    __syncthreads();
    const int c2 = t & 63;            // col pair 2c2, 2c2+1
    const int nh = (t >> 6) * 4;      // 4 rows
    float acc0[4], acc1[4];
    float b0 = bin_[2 * c2], b1 = bin_[2 * c2 + 1];
#pragma unroll
    for (int j = 0; j < 4; ++j) { acc0[j] = b0; acc1[j] = b1; }
    for (int k = 0; k < 69; ++k) {
        float w0 = Ws[k * 128 + 2 * c2];
        float w1 = Ws[k * 128 + 2 * c2 + 1];
#pragma unroll
        for (int j = 0; j < 4; ++j) {
            float a = As[(nh + j) * 70 + k];
            acc0[j] += a * w0;
            acc1[j] += a * w1;
        }
    }
#pragma unroll
    for (int j = 0; j < 4; ++j)
        h_bf[(size_t)(n0 + nh + j) * 64 + c2] = bfpack(acc0[j], acc1[j]);
}

// ---- CSR build: histogram -> scan -> scatter ----
__global__ __launch_bounds__(256) void csr_hist(
    const int* __restrict__ ei0, const int* __restrict__ ei1, const int* __restrict__ ei2,
    int* __restrict__ rp)
{
    int idx = blockIdx.x * 256 + threadIdx.x;
    if (idx >= 3 * EE) return;
    int r = idx / EE, e = idx - r * EE;
    const int* ei = (r == 0) ? ei0 : ((r == 1) ? ei1 : ei2);
    atomicAdd(&rp[r * SCAN_L + ei[EE + e] + 1], 1);
}

__global__ __launch_bounds__(256) void scan1(int* __restrict__ rp, int* __restrict__ bs)
{
    __shared__ int ts[256];
    const int r = blockIdx.y;
    int* a = rp + (size_t)r * SCAN_L;
    const int base = blockIdx.x * SCAN_EPB + threadIdx.x * SCAN_E;
    int v[SCAN_E];
    int tot = 0;
#pragma unroll
    for (int j = 0; j < SCAN_E; ++j) {
        int idx = base + j;
        v[j] = (idx < SCAN_L) ? a[idx] : 0;
        tot += v[j];
    }
    ts[threadIdx.x] = tot;
    __syncthreads();
    for (int st = 1; st < 256; st <<= 1) {
        int add = (threadIdx.x >= st) ? ts[threadIdx.x - st] : 0;
        __syncthreads();
        ts[threadIdx.x] += add;
        __syncthreads();
    }
    int run = ts[threadIdx.x] - tot;
#pragma unroll
    for (int j = 0; j < SCAN_E; ++j) {
        run += v[j];
        int idx = base + j;
        if (idx < SCAN_L) a[idx] = run;
    }
    if (threadIdx.x == 255) bs[r * 128 + blockIdx.x] = ts[255];
}

__global__ __launch_bounds__(128) void scan2(int* __restrict__ bs)
{
    __shared__ int ts[128];
    const int r = blockIdx.x, t = threadIdx.x;
    int v = (t < SCAN_NB) ? bs[r * 128 + t] : 0;
    ts[t] = v;
    __syncthreads();
    for (int st = 1; st < 128; st <<= 1) {
        int add = (t >= st) ? ts[t - st] : 0;
        __syncthreads();
        ts[t] += add;
        __syncthreads();
    }
    bs[r * 128 + t] = ts[t];
}

__global__ __launch_bounds__(256) void scan3(int* __restrict__ rp, const int* __restrict__ bs)
{
    const int r = blockIdx.y;
    if (blockIdx.x == 0) return;
    const int off = bs[r * 128 + blockIdx.x - 1];
    const int base = blockIdx.x * SCAN_EPB + threadIdx.x * SCAN_E;
    int* a = rp + (size_t)r * SCAN_L;
#pragma unroll
    for (int j = 0; j < SCAN_E; ++j) {
        int idx = base + j;
        if (idx < SCAN_L) a[idx] += off;
    }
}

__global__ __launch_bounds__(256) void csr_scatter(
    const int* __restrict__ ei0, const int* __restrict__ ei1, const int* __restrict__ ei2,
    const int* __restrict__ rp, int* __restrict__ fill,
    int* __restrict__ csrc, int* __restrict__ cdst)
{
    int idx = blockIdx.x * 256 + threadIdx.x;
    if (idx >= 3 * EE) return;
    int r = idx / EE, e = idx - r * EE;
    const int* ei = (r == 0) ? ei0 : ((r == 1) ? ei1 : ei2);
    int src = ei[e], dst = ei[EE + e];
    int pos = rp[r * SCAN_L + dst] + atomicAdd(&fill[r * NN + dst], 1);
    csrc[r * EE + pos] = src;
    cdst[r * EE + pos] = dst;
}

// ---- MFMA GEMM core (shared by 1-slot / 2-slot kernels) -------------------
// A-frag: A[m=lane&15][k=quad*8+j]; B-frag from W^T; C/D row=quad*4+reg, col=lane&15.
__device__ __forceinline__ void mfma_tile(
    const unsigned* Asm, const unsigned* Bsm, int m, int quad, int tc0,
    f32x4& acc00, f32x4& acc01, f32x4& acc10, f32x4& acc11)
{
#pragma unroll
    for (int kc = 0; kc < 4; ++kc) {
        const int koff = kc * 16 + quad * 4;
        bf16x8 a0 = *(const bf16x8*)&Asm[m * 68 + koff];
        bf16x8 a1 = *(const bf16x8*)&Asm[(16 + m) * 68 + koff];
        bf16x8 b0 = *(const bf16x8*)&Bsm[(tc0 * 16 + m) * 68 + koff];
        bf16x8 b1 = *(const bf16x8*)&Bsm[((tc0 + 1) * 16 + m) * 68 + koff];
        acc00 = __builtin_amdgcn_mfma_f32_16x16x32_bf16(a0, b0, acc00, 0, 0, 0);
        acc01 = __builtin_amdgcn_mfma_f32_16x16x32_bf16(a0, b1, acc01, 0, 0, 0);
        acc10 = __builtin_amdgcn_mfma_f32_16x16x32_bf16(a1, b0, acc10, 0, 0, 0);
        acc11 = __builtin_amdgcn_mfma_f32_16x16x32_bf16(a1, b1, acc11, 0, 0, 0);
    }
}

__device__ __forceinline__ void mfma_epilogue(
    float* Cs, int m, int quad, int tc0,
    const f32x4& acc00, const f32x4& acc01, const f32x4& acc10, const f32x4& acc11)
{
#pragma unroll
    for (int r = 0; r < 4; ++r) {
        Cs[(quad * 4 + r) * 132 + tc0 * 16 + m]            = acc00[r];
        Cs[(quad * 4 + r) * 132 + (tc0 + 1) * 16 + m]      = acc01[r];
        Cs[(16 + quad * 4 + r) * 132 + tc0 * 16 + m]       = acc10[r];
        Cs[(16 + quad * 4 + r) * 132 + (tc0 + 1) * 16 + m] = acc11[r];
    }
}

// ---- 1-slot MFMA GEMM: out = in_bf @ W + bias ----
__global__ __launch_bounds__(256) void gemm_mfma(
    const unsigned* __restrict__ in_bf, const unsigned* __restrict__ WT,
    const float* __restrict__ bias, unsigned* __restrict__ outp)
{
    __shared__ unsigned Asm[32 * 68];
    __shared__ unsigned Bsm[128 * 68];
    const int t = threadIdx.x;
    const int n0 = blockIdx.x * 32;
    for (int i = t; i < 32 * 16; i += 256) {
        int row = i >> 4, q4 = i & 15;
        uint4 v = *(const uint4*)(in_bf + (size_t)(n0 + row) * 64 + q4 * 4);
        *(uint4*)&Asm[row * 68 + q4 * 4] = v;
    }
    for (int i = t; i < 128 * 16; i += 256) {
        int row = i >> 4, q4 = i & 15;
        uint4 v = *(const uint4*)(WT + (size_t)row * 64 + q4 * 4);
        *(uint4*)&Bsm[row * 68 + q4 * 4] = v;
    }
    __syncthreads();
    const int w = t >> 6, lane = t & 63;
    const int m = lane & 15, quad = lane >> 4;
    const int tc0 = 2 * w;
    f32x4 acc00 = {0.f, 0.f, 0.f, 0.f}, acc01 = acc00, acc10 = acc00, acc11 = acc00;
    mfma_tile(Asm, Bsm, m, quad, tc0, acc00, acc01, acc10, acc11);
    __syncthreads();
    float* Cs = (float*)Bsm;
    mfma_epilogue(Cs, m, quad, tc0, acc00, acc01, acc10, acc11);
    __syncthreads();
    for (int i = t; i < 32 * 64; i += 256) {
        int row = i >> 6, c2 = i & 63;
        float c0 = Cs[row * 132 + 2 * c2]     + bias[2 * c2];
        float c1 = Cs[row * 132 + 2 * c2 + 1] + bias[2 * c2 + 1];
        outp[(size_t)(n0 + row) * 64 + c2] = bfpack(c0, c1);
    }
}

// ---- 2-slot MFMA GEMM: A staged once, two weight slots -> two outputs ----
__global__ __launch_bounds__(256) void gemm_mfma2(
    const unsigned* __restrict__ in_bf,
    const unsigned* __restrict__ WT0, const float* __restrict__ bias0,
    unsigned* __restrict__ out0,
    const unsigned* __restrict__ WT1, const float* __restrict__ bias1,
    unsigned* __restrict__ out1)
{
    __shared__ unsigned Asm[32 * 68];
    __shared__ unsigned Bsm[128 * 68];
    const int t = threadIdx.x;
    const int n0 = blockIdx.x * 32;
    const int w = t >> 6, lane = t & 63;
    const int m = lane & 15, quad = lane >> 4;
    const int tc0 = 2 * w;
    for (int i = t; i < 32 * 16; i += 256) {
        int row = i >> 4, q4 = i & 15;
        uint4 v = *(const uint4*)(in_bf + (size_t)(n0 + row) * 64 + q4 * 4);
        *(uint4*)&Asm[row * 68 + q4 * 4] = v;
    }
#pragma unroll
    for (int sl = 0; sl < 2; ++sl) {
        const unsigned* WT = sl ? WT1 : WT0;
        const float* bias = sl ? bias1 : bias0;
        unsigned* outp = sl ? out1 : out0;
        __syncthreads();                  // Bsm free (or drained from prev slot)
        for (int i = t; i < 128 * 16; i += 256) {
            int row = i >> 4, q4 = i & 15;
            uint4 v = *(const uint4*)(WT + (size_t)row * 64 + q4 * 4);
            *(uint4*)&Bsm[row * 68 + q4 * 4] = v;
        }
        __syncthreads();
        f32x4 acc00 = {0.f, 0.f, 0.f, 0.f}, acc01 = acc00, acc10 = acc00, acc11 = acc00;
        mfma_tile(Asm, Bsm, m, quad, tc0, acc00, acc01, acc10, acc11);
        __syncthreads();
        float* Cs = (float*)Bsm;
        mfma_epilogue(Cs, m, quad, tc0, acc00, acc01, acc10, acc11);
        __syncthreads();
        for (int i = t; i < 32 * 64; i += 256) {
            int row = i >> 6, c2 = i & 63;
            float c0 = Cs[row * 132 + 2 * c2]     + bias[2 * c2];
            float c1 = Cs[row * 132 + 2 * c2 + 1] + bias[2 * c2 + 1];
            outp[(size_t)(n0 + row) * 64 + c2] = bfpack(c0, c1);
        }
    }
}

// ---- edge scores in CSR position order ----
__global__ __launch_bounds__(256) void edge_scores_csr(
    const unsigned* __restrict__ q_bf, const unsigned* __restrict__ k_bf,
    const int* __restrict__ csrc, const int* __restrict__ cdst,
    const float* __restrict__ p4, float* __restrict__ s_out)
{
    int idx = blockIdx.x * 256 + threadIdx.x;
    if (idx >= EE * 4) return;
    int p = idx >> 2, hh = idx & 3;
    int src = csrc[p], dst = cdst[p];
    const uint4* qp = (const uint4*)(q_bf + (size_t)dst * 64 + hh * 16);
    const uint4* kp = (const uint4*)(k_bf + (size_t)src * 64 + hh * 16);
    float sum = 0.f;
#pragma unroll
    for (int i = 0; i < 4; ++i) {
        uint4 qa = qp[i], ka = kp[i];
        sum += bflo(qa.x) * bflo(ka.x) + bfhi(qa.x) * bfhi(ka.x);
        sum += bflo(qa.y) * bflo(ka.y) + bfhi(qa.y) * bfhi(ka.y);
        sum += bflo(qa.z) * bflo(ka.z) + bfhi(qa.z) * bfhi(ka.z);
        sum += bflo(qa.w) * bflo(ka.w) + bfhi(qa.w) * bfhi(ka.w);
    }
    s_out[(size_t)p * 4 + hh] = sum * p4[hh] * INV_SQRT_D;
}

// ---- CSR segment softmax: 2 passes (max; exp+sum). 1/Z stored for agg. ----
__global__ __launch_bounds__(256) void csr_softmax(
    float* __restrict__ s, const int* __restrict__ rp, float* __restrict__ invZ)
{
    const int dst = blockIdx.x * 4 + (threadIdx.x >> 6);
    const int lane = threadIdx.x & 63;
    const int sub = lane >> 2, hh = lane & 3;
    int beg[3], end[3];
#pragma unroll
    for (int r = 0; r < 3; ++r) {
        beg[r] = rp[r * SCAN_L + dst];
        end[r] = rp[r * SCAN_L + dst + 1];
    }
    float m = -INFINITY;
#pragma unroll
    for (int r = 0; r < 3; ++r)
        for (int p = beg[r] + sub; p < end[r]; p += 16)
            m = fmaxf(m, s[((size_t)r * EE + p) * 4 + hh]);
#pragma unroll
    for (int st = 4; st < 64; st <<= 1) m = fmaxf(m, __shfl_xor(m, st));
    float zz = 0.f;
#pragma unroll
    for (int r = 0; r < 3; ++r)
        for (int p = beg[r] + sub; p < end[r]; p += 16) {
            size_t off = ((size_t)r * EE + p) * 4 + hh;
            float ex = expf(s[off] - m);
            s[off] = ex;
            zz += ex;
        }
#pragma unroll
    for (int st = 4; st < 64; st <<= 1) zz += __shfl_xor(zz, st);
    if (sub == 0) invZ[(size_t)dst * 4 + hh] = 1.f / (zz + 1e-16f);
}

// ---- agg_reg: wave-per-dst register aggregation of TRANSFORMED vt planes.
//      s holds unnormalized exp; scale by invZ[dst] once at the end. ----
template<int NREL, int FIRST>
__global__ __launch_bounds__(256, 8) void agg_reg(
    const unsigned* __restrict__ pA, const unsigned* __restrict__ pB,
    const float* __restrict__ s, const int* __restrict__ rp,
    const int* __restrict__ csrc, int ra, int rb,
    const float* __restrict__ invZ, unsigned* __restrict__ As_g)
{
    const int dst = blockIdx.x * 4 + (threadIdx.x >> 6);
    const int lane = threadIdx.x & 63;
    const int hh = lane >> 4;
    float a0 = 0.f, a1 = 0.f;
#pragma unroll
    for (int q = 0; q < NREL; ++q) {
        const unsigned* pl = q ? pB : pA;
        const int r = q ? rb : ra;
        const int beg = rp[r * SCAN_L + dst];
        const int end = rp[r * SCAN_L + dst + 1];
        int p = beg;
        for (; p + 1 < end; p += 2) {       // 2 independent gathers in flight
            int s0 = csrc[r * EE + p];
            float al0 = s[((size_t)r * EE + p) * 4 + hh];
            int s1 = csrc[r * EE + p + 1];
            float al1 = s[((size_t)r * EE + p + 1) * 4 + hh];
            unsigned v0 = pl[(size_t)s0 * 64 + lane];
            unsigned v1 = pl[(size_t)s1 * 64 + lane];
            a0 += al0 * bflo(v0) + al1 * bflo(v1);
            a1 += al0 * bfhi(v0) + al1 * bfhi(v1);
        }
        if (p < end) {
            int s0 = csrc[r * EE + p];
            float al0 = s[((size_t)r * EE + p) * 4 + hh];
            unsigned v0 = pl[(size_t)s0 * 64 + lane];
            a0 += al0 * bflo(v0);
            a1 += al0 * bfhi(v0);
        }
    }
    float iz = invZ[(size_t)dst * 4 + hh];
    a0 *= iz; a1 *= iz;
    size_t off = (size_t)dst * 64 + lane;
    if (FIRST) {
        As_g[off] = bfpack(a0, a1);
    } else {
        unsigned old = As_g[off];
        As_g[off] = bfpack(bflo(old) + a0, bfhi(old) + a1);
    }
}

// ---- out_ln (MFMA core): gelu(As) @ Wout + bout -> skip -> LayerNorm -> h (bf16) ----
__global__ __launch_bounds__(256) void out_ln(
    const unsigned* __restrict__ As_g, unsigned* __restrict__ h_bf,
    const unsigned* __restrict__ WT, const float* __restrict__ bout,
    const float* __restrict__ skipp, const float* __restrict__ lg,
    const float* __restrict__ lb)
{
    __shared__ unsigned Asm[32 * 68];
    __shared__ unsigned Bsm[128 * 68];
    const int t = threadIdx.x;
    const int n0 = blockIdx.x * 32;
    for (int i = t; i < 32 * 64; i += 256) {
        int row = i >> 6, c2 = i & 63;
        unsigned u = As_g[(size_t)(n0 + row) * 64 + c2];
        Asm[row * 68 + c2] = bfpack(gelu_exact(bflo(u)), gelu_exact(bfhi(u)));
    }
    for (int i = t; i < 128 * 16; i += 256) {
        int row = i >> 4, q4 = i & 15;
        uint4 v = *(const uint4*)(WT + (size_t)row * 64 + q4 * 4);
        *(uint4*)&Bsm[row * 68 + q4 * 4] = v;
    }
    __syncthreads();
    const int w = t >> 6, lane = t & 63;
    const int m = lane & 15, quad = lane >> 4;
    const int tc0 = 2 * w;
    f32x4 acc00 = {0.f, 0.f, 0.f, 0.f}, acc01 = acc00, acc10 = acc00, acc11 = acc00;
    mfma_tile(Asm, Bsm, m, quad, tc0, acc00, acc01, acc10, acc11);
    __syncthreads();
    float* Cs = (float*)Bsm;
    mfma_epilogue(Cs, m, quad, tc0, acc00, acc01, acc10, acc11);
    __syncthreads();
    const int cg = t & 31;            // cols 4cg..4cg+3
    const int rg = (t >> 5) * 4;      // rows rg..rg+3
    float4 bv = *(const float4*)(bout + 4 * cg);
    const float alpha = 1.f / (1.f + expf(-skipp[0]));
    const float om = 1.f - alpha;
    float4 g4 = *(const float4*)(lg + 4 * cg);
    float4 b4 = *(const float4*)(lb + 4 * cg);
#pragma unroll
    for (int i = 0; i < 4; ++i) {
        const size_t n = (size_t)(n0 + rg + i);
        float4 cc = *(const float4*)(Cs + (rg + i) * 132 + 4 * cg);
        uint2 hu = *(const uint2*)(h_bf + n * 64 + 2 * cg);
        float o0 = alpha * (cc.x + bv.x) + om * bflo(hu.x);
        float o1 = alpha * (cc.y + bv.y) + om * bfhi(hu.x);
        float o2 = alpha * (cc.z + bv.z) + om * bflo(hu.y);
        float o3 = alpha * (cc.w + bv.w) + om * bfhi(hu.y);
        float sm = o0 + o1 + o2 + o3;
#pragma unroll
        for (int mm = 1; mm < 32; mm <<= 1) sm += __shfl_xor(sm, mm);
        float mu = sm * (1.f / 128.f);
        float d0 = o0 - mu, d1 = o1 - mu, d2 = o2 - mu, d3 = o3 - mu;
        float sq = d0 * d0 + d1 * d1 + d2 * d2 + d3 * d3;
#pragma unroll
        for (int mm = 1; mm < 32; mm <<= 1) sq += __shfl_xor(sq, mm);
        float rs = rsqrtf(sq * (1.f / 128.f) + 1e-5f);
        uint2 o = make_uint2(
            bfpack(d0 * rs * g4.x + b4.x, d1 * rs * g4.y + b4.y),
            bfpack(d2 * rs * g4.z + b4.z, d3 * rs * g4.w + b4.w));
        *(uint2*)(h_bf + n * 64 + 2 * cg) = o;
    }
}

// ---- masked mean-pool partials: 8 rows preloaded into registers (MLP fix) ----
__global__ __launch_bounds__(256) void pool_partial(
    const unsigned* __restrict__ h_bf, const float* __restrict__ x,
    const int* __restrict__ batch, float* __restrict__ psum, float* __restrict__ pcnt)
{
    const int c2b = threadIdx.x & 31;          // uint2 index: cols 4c2b .. 4c2b+3
    const int grp = threadIdx.x >> 5;          // 8 groups x 8 rows = 64 rows/block
    const int n0 = blockIdx.x * 64 + grp * 8;
    uint2 hv[8]; int bt[8]; float wv[8];
#pragma unroll
    for (int i = 0; i < 8; ++i) {              // 24 independent loads in flight
        int n = n0 + i;
        hv[i] = *(const uint2*)(h_bf + (size_t)n * 64 + 2 * c2b);
        bt[i] = batch[n];
        wv[i] = (x[(size_t)n * 5 + 1] > 0.f) ? 1.f : 0.f;
    }
    int g = bt[0];
    float sw[4] = {0.f, 0.f, 0.f, 0.f}, sn[4] = {0.f, 0.f, 0.f, 0.f};
    float cw = 0.f, cn = 0.f;
#pragma unroll
    for (int i = 0; i < 8; ++i) {
        if (bt[i] != g) {
#pragma unroll
            for (int j = 0; j < 4; ++j) {
                atomicAdd(&psum[g * 256 + 4 * c2b + j], sw[j]);
                atomicAdd(&psum[g * 256 + 128 + 4 * c2b + j], sn[j]);
                sw[j] = 0.f; sn[j] = 0.f;
            }
            if (c2b == 0) { atomicAdd(&pcnt[g * 2], cw); atomicAdd(&pcnt[g * 2 + 1], cn); }
            cw = cn = 0.f;
            g = bt[i];
        }
        float w = wv[i], nw = 1.f - w;
        float h0 = bflo(hv[i].x), h1 = bfhi(hv[i].x);
        float h2 = bflo(hv[i].y), h3 = bfhi(hv[i].y);
        sw[0] += w * h0; sw[1] += w * h1; sw[2] += w * h2; sw[3] += w * h3;
        sn[0] += nw * h0; sn[1] += nw * h1; sn[2] += nw * h2; sn[3] += nw * h3;
        cw += w; cn += nw;
    }
#pragma unroll
    for (int j = 0; j < 4; ++j) {
        atomicAdd(&psum[g * 256 + 4 * c2b + j], sw[j]);
        atomicAdd(&psum[g * 256 + 128 + 4 * c2b + j], sn[j]);
    }
    if (c2b == 0) { atomicAdd(&pcnt[g * 2], cw); atomicAdd(&pcnt[g * 2 + 1], cn); }
}

// ---------------- MLP head (pool finalize fused) ----------------
__global__ __launch_bounds__(256) void head_kernel(
    const float* __restrict__ psum, const float* __restrict__ pcnt,
    const float* __restrict__ task,
    const float* __restrict__ Wtf, const float* __restrict__ btf,
    const float* __restrict__ Wc1, const float* __restrict__ bc1,
    const float* __restrict__ Wc2, const float* __restrict__ bc2,
    float* __restrict__ out)
{
    __shared__ float in_s[640];
    __shared__ float ge_s[256];
    __shared__ float hc_s[64];
    const int b = blockIdx.x, t = threadIdx.x;
    if (t < 256) {
        float cnt = pcnt[b * 2 + (t >> 7)];
        float sv = psum[b * 256 + t];
        in_s[t] = (cnt > 0.f) ? sv / fmaxf(cnt, 1.f) : 0.f;
    }
    for (int i = t; i < 384; i += 256) in_s[256 + i] = task[b * 384 + i];
    __syncthreads();
    float acc = btf[t];
    for (int i = 0; i < 640; ++i) acc += in_s[i] * Wtf[i * 256 + t];
    ge_s[t] = fmaxf(acc, 0.f);
    __syncthreads();
    if (t < 64) {
        float a2 = bc1[t];
        for (int i = 0; i < 256; ++i) a2 += ge_s[i] * Wc1[i * 64 + t];
        hc_s[t] = fmaxf(a2, 0.f);
    }
    __syncthreads();
    if (t < 64) {
        float v = hc_s[t] * Wc2[t];
#pragma unroll
        for (int off = 32; off >= 1; off >>= 1) v += __shfl_down(v, off);
        if (t == 0) out[b] = v + bc2[0];
    }
}

__global__ __launch_bounds__(256) void zero_kernel(float4* __restrict__ p, int count4)
{
    int i = blockIdx.x * 256 + threadIdx.x;
    if (i < count4) p[i] = make_float4(0.f, 0.f, 0.f, 0.f);
}

extern "C" void kernel_launch(void* const* d_in, const int* in_sizes, int n_in,
                              void* d_out, int out_size, void* d_ws, size_t ws_size,
                              hipStream_t stream)
{
    const float* x      = (const float*)d_in[0];
    const int*   ast    = (const int*)d_in[1];
    const int*   batch  = (const int*)d_in[2];
    const int*   ei[3]  = {(const int*)d_in[3], (const int*)d_in[4], (const int*)d_in[5]};
    const float* task   = (const float*)d_in[6];
    const float* emb    = (const float*)d_in[7];
    const float* Win    = (const float*)d_in[8];
    const float* bin_   = (const float*)d_in[9];
    const float* Wkqv   = (const float*)d_in[10];
    const float* bkqv   = (const float*)d_in[11];
    const float* Wk_rel = (const float*)d_in[12];
    const float* Wv_rel = (const float*)d_in[13];
    const float* p_rel  = (const float*)d_in[14];
    const float* Wout   = (const float*)d_in[15];
    const float* bout   = (const float*)d_in[16];
    const float* skip   = (const float*)d_in[17];
    const float* ln_g   = (const float*)d_in[18];
    const float* ln_b   = (const float*)d_in[19];
    const float* Wtf    = (const float*)d_in[20];
    const float* btf    = (const float*)d_in[21];
    const float* Wc1    = (const float*)d_in[22];
    const float* bc1    = (const float*)d_in[23];
    const float* Wc2    = (const float*)d_in[24];
    const float* bc2    = (const float*)d_in[25];
    float* out = (float*)d_out;
    float* ws  = (float*)d_ws;

    unsigned* hB   = (unsigned*)(ws + OFF_HB);
    unsigned* P0   = (unsigned*)(ws + OFF_P0);   // q -> vt_0 -> vt_2
    unsigned* P1   = (unsigned*)(ws + OFF_P1);   // kt_r -> vt_1
    unsigned* AS   = (unsigned*)(ws + OFF_AS);
    float*    sbuf = ws + OFF_S;
    int*      rp   = (int*)(ws + OFF_RP);
    int*      csrc = (int*)(ws + OFF_CSRC);
    int*      cdst = (int*)(ws + OFF_CDST);
    int*      fill = (int*)(ws + OFF_P0);        // aliases P0 during CSR build only
    float*    Wf   = ws + OFF_WF;
    float*    bf   = ws + OFF_BF;
    int*      bs   = (int*)(ws + OFF_BS);
    float*    psum = ws + OFF_POOL;
    float*    pcnt = psum + (size_t)BB * 256;
    unsigned* WT   = (unsigned*)(ws + OFF_WT);   // 14 gemm slots + 2 Wout slots
    float*    invZ = ws + OFF_IZ;

    fold_weights<<<14, 256, 0, stream>>>(Wkqv, bkqv, Wk_rel, Wv_rel, Wf, bf);
    pack_wt<<<14, 256, 0, stream>>>(Wf, WT);
    pack_wt<<<2, 256, 0, stream>>>(Wout, WT + (size_t)14 * 8192);
    input_proj<<<NN / 16, 256, 0, stream>>>(x, ast, emb, Win, bin_, hB);

    zero_kernel<<<(600016 / 4 + 255) / 256, 256, 0, stream>>>((float4*)rp, 600016 / 4);
    zero_kernel<<<(600000 / 4 + 255) / 256, 256, 0, stream>>>((float4*)fill, 600000 / 4);
    csr_hist<<<(3 * EE + 255) / 256, 256, 0, stream>>>(ei[0], ei[1], ei[2], rp);
    scan1<<<dim3(SCAN_NB, 3), 256, 0, stream>>>(rp, bs);
    scan2<<<3, 128, 0, stream>>>(bs);
    scan3<<<dim3(SCAN_NB, 3), 256, 0, stream>>>(rp, bs);
    csr_scatter<<<(3 * EE + 255) / 256, 256, 0, stream>>>(
        ei[0], ei[1], ei[2], rp, fill, csrc, cdst);

    for (int l = 0; l < 2; ++l) {
        const size_t ls = (size_t)l * 7;   // slots: 0=q, 1..3=kt_r, 4..6=vt_r
        // q + kt_0 share one A-staging
        gemm_mfma2<<<NN / 32, 256, 0, stream>>>(
            hB, WT + ls * 8192, bf + ls * 128, P0,
            WT + (ls + 1) * 8192, bf + (ls + 1) * 128, P1);
        edge_scores_csr<<<(EE * 4 + 255) / 256, 256, 0, stream>>>(
            P0, P1, csrc, cdst, p_rel + (size_t)l * 12, sbuf);
        for (int r = 1; r < 3; ++r) {
            gemm_mfma<<<NN / 32, 256, 0, stream>>>(
                hB, WT + (ls + 1 + r) * 8192, bf + (ls + 1 + r) * 128, P1);
            edge_scores_csr<<<(EE * 4 + 255) / 256, 256, 0, stream>>>(
                P0, P1, csrc + (size_t)r * EE, cdst + (size_t)r * EE,
                p_rel + (size_t)(l * 3 + r) * 4, sbuf + (size_t)r * EE * 4);
        }
        csr_softmax<<<NN / 4, 256, 0, stream>>>(sbuf, rp, invZ);
        // phase B: q dead -> P0 = vt_0; kt dead -> P1 = vt_1; then P0 = vt_2
        gemm_mfma2<<<NN / 32, 256, 0, stream>>>(
            hB, WT + (ls + 4) * 8192, bf + (ls + 4) * 128, P0,
            WT + (ls + 5) * 8192, bf + (ls + 5) * 128, P1);
        agg_reg<2, 1><<<NN / 4, 256, 0, stream>>>(P0, P1, sbuf, rp, csrc, 0, 1, invZ, AS);
        gemm_mfma<<<NN / 32, 256, 0, stream>>>(hB, WT + (ls + 6) * 8192, bf + (ls + 6) * 128, P0);
        agg_reg<1, 0><<<NN / 4, 256, 0, stream>>>(P0, P0, sbuf, rp, csrc, 2, 2, invZ, AS);
        out_ln<<<NN / 32, 256, 0, stream>>>(
            AS, hB, WT + (size_t)(14 + l) * 8192, bout + (size_t)l * 128,
            skip + l, ln_g + (size_t)l * 128, ln_b + (size_t)l * 128);
    }

    zero_kernel<<<(16512 / 4 + 255) / 256, 256, 0, stream>>>((float4*)psum, 16512 / 4);
    pool_partial<<<NN / 64, 256, 0, stream>>>(hB, x, batch, psum, pcnt);
    head_kernel<<<BB, 256, 0, stream>>>(psum, pcnt, task, Wtf, btf, Wc1, bc1, Wc2, bc2, out);
}

// Round 14
// 1505.712 us; speedup vs baseline: 1.1637x; 1.1637x over previous
//
#include <hip/hip_runtime.h>
#include <math.h>

// Problem constants (match reference)
#define NN 200000
#define EE 300000
#define BB 64
#define INV_SQRT_D 0.17677669529663687f

// ---- workspace layout in 4-byte words. Total ≈ 58.38M words = 233.5 MB.
// ws budget is ~256MB-class (252 passed, 329 faulted) -> stay <= 252 MB.
#define OFF_HB   ((size_t)0)                    // [N][64] uint (bf16x2) node features
#define OFF_P0   ((size_t)12800000)             // [N][64] uint: q, then vt_0, then vt_2
#define OFF_P1   ((size_t)25600000)             // [N][64] uint: kt_r, then vt_1
#define OFF_AS   ((size_t)38400000)             // [N][64] uint: As accumulator (bf16)
#define OFF_S    ((size_t)51200000)             // [3][E][4] f32 scores -> exp (CSR order)
#define OFF_RP   ((size_t)54800000)             // [3][N+1] int rowptr (padded 600016)
#define OFF_CSRC ((size_t)55400016)             // [3][E] int src per CSR position
#define OFF_CDST ((size_t)56300016)             // [3][E] int dst per CSR position
#define OFF_WF   ((size_t)57200016)             // 14 x [128][128] f32 folded weights
#define OFF_BF   ((size_t)57429392)             // 14 x [128] f32 folded bias
#define OFF_BS   ((size_t)57431184)             // scan block sums 3*128 int
#define OFF_POOL ((size_t)57431568)             // psum [B][256] + pcnt [B][2] (16512)
#define OFF_WT   ((size_t)57448080)             // 16 x [128][64] uint packed W^T
#define OFF_IZ   ((size_t)57579152)             // [N][4] f32 softmax 1/Z

#define SCAN_L   (NN + 1)
#define SCAN_E   8
#define SCAN_EPB (256 * SCAN_E)                          // 2048
#define SCAN_NB  ((SCAN_L + SCAN_EPB - 1) / SCAN_EPB)    // 98

typedef __attribute__((ext_vector_type(8))) short bf16x8;
typedef __attribute__((ext_vector_type(4))) float f32x4;

__device__ __forceinline__ float gelu_exact(float v) {
    return 0.5f * v * (1.0f + erff(v * 0.70710678118654752f));
}
__device__ __forceinline__ float bflo(unsigned u) { return __uint_as_float(u << 16); }
__device__ __forceinline__ float bfhi(unsigned u) { return __uint_as_float(u & 0xffff0000u); }
__device__ __forceinline__ unsigned bfpack(float a, float b) {
    unsigned ua = __float_as_uint(a); ua += 0x7fffu + ((ua >> 16) & 1u);
    unsigned ub = __float_as_uint(b); ub += 0x7fffu + ((ub >> 16) & 1u);
    return (ua >> 16) | (ub & 0xffff0000u);
}

// ---- fold weights. 14 slots: per layer l: [l*7+0]=q copy, [l*7+1+r]=k@Wk_rel[r],
//      [l*7+4+r]=v@Wv_rel[r].  kqv split order is k|q|v (cols 0/128/256).
__global__ __launch_bounds__(256) void fold_weights(
    const float* __restrict__ Wkqv, const float* __restrict__ bkqv,
    const float* __restrict__ Wk_rel, const float* __restrict__ Wv_rel,
    float* __restrict__ Wf, float* __restrict__ bf)
{
    __shared__ float Wr[4096];
    const int b = blockIdx.x, t = threadIdx.x;
    const int l = b / 7, s = b % 7;
    const float* Wq = Wkqv + (size_t)l * 49152;   // [128][384]
    if (s == 0) {
        for (int i = t; i < 16384; i += 256) {
            int kk = i >> 7, c = i & 127;
            Wf[(size_t)b * 16384 + i] = Wq[kk * 384 + 128 + c];
        }
        if (t < 128) bf[b * 128 + t] = bkqv[l * 384 + 128 + t];
    } else {
        const int side = (s - 1) / 3, r = (s - 1) % 3;
        const int off = side ? 256 : 0;
        const float* Wrel = (side ? Wv_rel : Wk_rel) + (size_t)(l * 3 + r) * 4096;
        for (int i = t; i < 4096; i += 256) Wr[i] = Wrel[i];
        __syncthreads();
        for (int i = t; i < 16384; i += 256) {
            int kk = i >> 7, c = i & 127, hh = c >> 5, f = c & 31;
            const float* wrow = Wq + kk * 384 + off + hh * 32;
            const float* wr = Wr + hh * 1024 + f;
            float sum = 0.f;
#pragma unroll
            for (int d = 0; d < 32; ++d) sum += wrow[d] * wr[d * 32];
            Wf[(size_t)b * 16384 + i] = sum;
        }
        if (t < 128) {
            int hh = t >> 5, f = t & 31;
            float sum = 0.f;
#pragma unroll
            for (int d = 0; d < 32; ++d)
                sum += bkqv[l * 384 + off + hh * 32 + d] * Wr[hh * 1024 + d * 32 + f];
            bf[b * 128 + t] = sum;
        }
    }
}

// ---- pack W -> bf16x2-packed W^T: WT[slot][c][w] = (W[2w][c], W[2w+1][c]) ----
__global__ __launch_bounds__(256) void pack_wt(
    const float* __restrict__ W, unsigned* __restrict__ WT)
{
    const int slot = blockIdx.x, t = threadIdx.x;
    const float* Ws = W + (size_t)slot * 16384;
    unsigned* WTs = WT + (size_t)slot * 8192;
    for (int i = t; i < 8192; i += 256) {
        int c = i >> 6, w = i & 63;
        WTs[i] = bfpack(Ws[(size_t)(2 * w) * 128 + c], Ws[(size_t)(2 * w + 1) * 128 + c]);
    }
}

// ---------------- input projection: h_bf = bf16([emb[ast], x] @ Win + bin) ----------------
__global__ __launch_bounds__(256) void input_proj(
    const float* __restrict__ x, const int* __restrict__ ast,
    const float* __restrict__ emb, const float* __restrict__ Win,
    const float* __restrict__ bin_, unsigned* __restrict__ h_bf)
{
    __shared__ float Ws[69 * 128];
    __shared__ float As[16 * 70];
    const int t = threadIdx.x;
    const int n0 = blockIdx.x * 16;
    for (int i = t; i < 69 * 128; i += 256) Ws[i] = Win[i];
    for (int i = t; i < 16 * 69; i += 256) {
        int nl = i / 69, kk = i - nl * 69;
        int n = n0 + nl;
        float v = (kk < 64) ? emb[ast[n] * 64 + kk] : x[n * 5 + (kk - 64)];
        As[nl * 70 + kk] = v;
    }
    __syncthreads();
    const int c2 = t & 63;            // col pair 2c2, 2c2+1
    const int nh = (t >> 6) * 4;      // 4 rows
    float acc0[4], acc1[4];
    float b0 = bin_[2 * c2], b1 = bin_[2 * c2 + 1];
#pragma unroll
    for (int j = 0; j < 4; ++j) { acc0[j] = b0; acc1[j] = b1; }
    for (int k = 0; k < 69; ++k) {
        float w0 = Ws[k * 128 + 2 * c2];
        float w1 = Ws[k * 128 + 2 * c2 + 1];
#pragma unroll
        for (int j = 0; j < 4; ++j) {
            float a = As[(nh + j) * 70 + k];
            acc0[j] += a * w0;
            acc1[j] += a * w1;
        }
    }
#pragma unroll
    for (int j = 0; j < 4; ++j)
        h_bf[(size_t)(n0 + nh + j) * 64 + c2] = bfpack(acc0[j], acc1[j]);
}

// ---- CSR build: histogram -> scan -> scatter ----
__global__ __launch_bounds__(256) void csr_hist(
    const int* __restrict__ ei0, const int* __restrict__ ei1, const int* __restrict__ ei2,
    int* __restrict__ rp)
{
    int idx = blockIdx.x * 256 + threadIdx.x;
    if (idx >= 3 * EE) return;
    int r = idx / EE, e = idx - r * EE;
    const int* ei = (r == 0) ? ei0 : ((r == 1) ? ei1 : ei2);
    atomicAdd(&rp[r * SCAN_L + ei[EE + e] + 1], 1);
}

__global__ __launch_bounds__(256) void scan1(int* __restrict__ rp, int* __restrict__ bs)
{
    __shared__ int ts[256];
    const int r = blockIdx.y;
    int* a = rp + (size_t)r * SCAN_L;
    const int base = blockIdx.x * SCAN_EPB + threadIdx.x * SCAN_E;
    int v[SCAN_E];
    int tot = 0;
#pragma unroll
    for (int j = 0; j < SCAN_E; ++j) {
        int idx = base + j;
        v[j] = (idx < SCAN_L) ? a[idx] : 0;
        tot += v[j];
    }
    ts[threadIdx.x] = tot;
    __syncthreads();
    for (int st = 1; st < 256; st <<= 1) {
        int add = (threadIdx.x >= st) ? ts[threadIdx.x - st] : 0;
        __syncthreads();
        ts[threadIdx.x] += add;
        __syncthreads();
    }
    int run = ts[threadIdx.x] - tot;
#pragma unroll
    for (int j = 0; j < SCAN_E; ++j) {
        run += v[j];
        int idx = base + j;
        if (idx < SCAN_L) a[idx] = run;
    }
    if (threadIdx.x == 255) bs[r * 128 + blockIdx.x] = ts[255];
}

__global__ __launch_bounds__(128) void scan2(int* __restrict__ bs)
{
    __shared__ int ts[128];
    const int r = blockIdx.x, t = threadIdx.x;
    int v = (t < SCAN_NB) ? bs[r * 128 + t] : 0;
    ts[t] = v;
    __syncthreads();
    for (int st = 1; st < 128; st <<= 1) {
        int add = (t >= st) ? ts[t - st] : 0;
        __syncthreads();
        ts[t] += add;
        __syncthreads();
    }
    bs[r * 128 + t] = ts[t];
}

__global__ __launch_bounds__(256) void scan3(int* __restrict__ rp, const int* __restrict__ bs)
{
    const int r = blockIdx.y;
    if (blockIdx.x == 0) return;
    const int off = bs[r * 128 + blockIdx.x - 1];
    const int base = blockIdx.x * SCAN_EPB + threadIdx.x * SCAN_E;
    int* a = rp + (size_t)r * SCAN_L;
#pragma unroll
    for (int j = 0; j < SCAN_E; ++j) {
        int idx = base + j;
        if (idx < SCAN_L) a[idx] += off;
    }
}

__global__ __launch_bounds__(256) void csr_scatter(
    const int* __restrict__ ei0, const int* __restrict__ ei1, const int* __restrict__ ei2,
    const int* __restrict__ rp, int* __restrict__ fill,
    int* __restrict__ csrc, int* __restrict__ cdst)
{
    int idx = blockIdx.x * 256 + threadIdx.x;
    if (idx >= 3 * EE) return;
    int r = idx / EE, e = idx - r * EE;
    const int* ei = (r == 0) ? ei0 : ((r == 1) ? ei1 : ei2);
    int src = ei[e], dst = ei[EE + e];
    int pos = rp[r * SCAN_L + dst] + atomicAdd(&fill[r * NN + dst], 1);
    csrc[r * EE + pos] = src;
    cdst[r * EE + pos] = dst;
}

// ---- MFMA GEMM core (shared by 1-slot / 2-slot kernels) -------------------
// A-frag: A[m=lane&15][k=quad*8+j]; B-frag from W^T; C/D row=quad*4+reg, col=lane&15.
__device__ __forceinline__ void mfma_tile(
    const unsigned* Asm, const unsigned* Bsm, int m, int quad, int tc0,
    f32x4& acc00, f32x4& acc01, f32x4& acc10, f32x4& acc11)
{
#pragma unroll
    for (int kc = 0; kc < 4; ++kc) {
        const int koff = kc * 16 + quad * 4;
        bf16x8 a0 = *(const bf16x8*)&Asm[m * 68 + koff];
        bf16x8 a1 = *(const bf16x8*)&Asm[(16 + m) * 68 + koff];
        bf16x8 b0 = *(const bf16x8*)&Bsm[(tc0 * 16 + m) * 68 + koff];
        bf16x8 b1 = *(const bf16x8*)&Bsm[((tc0 + 1) * 16 + m) * 68 + koff];
        acc00 = __builtin_amdgcn_mfma_f32_16x16x32_bf16(a0, b0, acc00, 0, 0, 0);
        acc01 = __builtin_amdgcn_mfma_f32_16x16x32_bf16(a0, b1, acc01, 0, 0, 0);
        acc10 = __builtin_amdgcn_mfma_f32_16x16x32_bf16(a1, b0, acc10, 0, 0, 0);
        acc11 = __builtin_amdgcn_mfma_f32_16x16x32_bf16(a1, b1, acc11, 0, 0, 0);
    }
}

__device__ __forceinline__ void mfma_epilogue(
    float* Cs, int m, int quad, int tc0,
    const f32x4& acc00, const f32x4& acc01, const f32x4& acc10, const f32x4& acc11)
{
#pragma unroll
    for (int r = 0; r < 4; ++r) {
        Cs[(quad * 4 + r) * 132 + tc0 * 16 + m]            = acc00[r];
        Cs[(quad * 4 + r) * 132 + (tc0 + 1) * 16 + m]      = acc01[r];
        Cs[(16 + quad * 4 + r) * 132 + tc0 * 16 + m]       = acc10[r];
        Cs[(16 + quad * 4 + r) * 132 + (tc0 + 1) * 16 + m] = acc11[r];
    }
}

// ---- 1-slot MFMA GEMM: out = in_bf @ W + bias ----
__global__ __launch_bounds__(256) void gemm_mfma(
    const unsigned* __restrict__ in_bf, const unsigned* __restrict__ WT,
    const float* __restrict__ bias, unsigned* __restrict__ outp)
{
    __shared__ unsigned Asm[32 * 68];
    __shared__ unsigned Bsm[128 * 68];
    const int t = threadIdx.x;
    const int n0 = blockIdx.x * 32;
    for (int i = t; i < 32 * 16; i += 256) {
        int row = i >> 4, q4 = i & 15;
        uint4 v = *(const uint4*)(in_bf + (size_t)(n0 + row) * 64 + q4 * 4);
        *(uint4*)&Asm[row * 68 + q4 * 4] = v;
    }
    for (int i = t; i < 128 * 16; i += 256) {
        int row = i >> 4, q4 = i & 15;
        uint4 v = *(const uint4*)(WT + (size_t)row * 64 + q4 * 4);
        *(uint4*)&Bsm[row * 68 + q4 * 4] = v;
    }
    __syncthreads();
    const int w = t >> 6, lane = t & 63;
    const int m = lane & 15, quad = lane >> 4;
    const int tc0 = 2 * w;
    f32x4 acc00 = {0.f, 0.f, 0.f, 0.f}, acc01 = acc00, acc10 = acc00, acc11 = acc00;
    mfma_tile(Asm, Bsm, m, quad, tc0, acc00, acc01, acc10, acc11);
    __syncthreads();
    float* Cs = (float*)Bsm;
    mfma_epilogue(Cs, m, quad, tc0, acc00, acc01, acc10, acc11);
    __syncthreads();
    for (int i = t; i < 32 * 64; i += 256) {
        int row = i >> 6, c2 = i & 63;
        float c0 = Cs[row * 132 + 2 * c2]     + bias[2 * c2];
        float c1 = Cs[row * 132 + 2 * c2 + 1] + bias[2 * c2 + 1];
        outp[(size_t)(n0 + row) * 64 + c2] = bfpack(c0, c1);
    }
}

// ---- 2-slot MFMA GEMM: A staged once, two weight slots -> two outputs ----
__global__ __launch_bounds__(256) void gemm_mfma2(
    const unsigned* __restrict__ in_bf,
    const unsigned* __restrict__ WT0, const float* __restrict__ bias0,
    unsigned* __restrict__ out0,
    const unsigned* __restrict__ WT1, const float* __restrict__ bias1,
    unsigned* __restrict__ out1)
{
    __shared__ unsigned Asm[32 * 68];
    __shared__ unsigned Bsm[128 * 68];
    const int t = threadIdx.x;
    const int n0 = blockIdx.x * 32;
    const int w = t >> 6, lane = t & 63;
    const int m = lane & 15, quad = lane >> 4;
    const int tc0 = 2 * w;
    for (int i = t; i < 32 * 16; i += 256) {
        int row = i >> 4, q4 = i & 15;
        uint4 v = *(const uint4*)(in_bf + (size_t)(n0 + row) * 64 + q4 * 4);
        *(uint4*)&Asm[row * 68 + q4 * 4] = v;
    }
#pragma unroll
    for (int sl = 0; sl < 2; ++sl) {
        const unsigned* WT = sl ? WT1 : WT0;
        const float* bias = sl ? bias1 : bias0;
        unsigned* outp = sl ? out1 : out0;
        __syncthreads();                  // Bsm free (or drained from prev slot)
        for (int i = t; i < 128 * 16; i += 256) {
            int row = i >> 4, q4 = i & 15;
            uint4 v = *(const uint4*)(WT + (size_t)row * 64 + q4 * 4);
            *(uint4*)&Bsm[row * 68 + q4 * 4] = v;
        }
        __syncthreads();
        f32x4 acc00 = {0.f, 0.f, 0.f, 0.f}, acc01 = acc00, acc10 = acc00, acc11 = acc00;
        mfma_tile(Asm, Bsm, m, quad, tc0, acc00, acc01, acc10, acc11);
        __syncthreads();
        float* Cs = (float*)Bsm;
        mfma_epilogue(Cs, m, quad, tc0, acc00, acc01, acc10, acc11);
        __syncthreads();
        for (int i = t; i < 32 * 64; i += 256) {
            int row = i >> 6, c2 = i & 63;
            float c0 = Cs[row * 132 + 2 * c2]     + bias[2 * c2];
            float c1 = Cs[row * 132 + 2 * c2 + 1] + bias[2 * c2 + 1];
            outp[(size_t)(n0 + row) * 64 + c2] = bfpack(c0, c1);
        }
    }
}

// ---- edge scores in CSR position order ----
__global__ __launch_bounds__(256) void edge_scores_csr(
    const unsigned* __restrict__ q_bf, const unsigned* __restrict__ k_bf,
    const int* __restrict__ csrc, const int* __restrict__ cdst,
    const float* __restrict__ p4, float* __restrict__ s_out)
{
    int idx = blockIdx.x * 256 + threadIdx.x;
    if (idx >= EE * 4) return;
    int p = idx >> 2, hh = idx & 3;
    int src = csrc[p], dst = cdst[p];
    const uint4* qp = (const uint4*)(q_bf + (size_t)dst * 64 + hh * 16);
    const uint4* kp = (const uint4*)(k_bf + (size_t)src * 64 + hh * 16);
    float sum = 0.f;
#pragma unroll
    for (int i = 0; i < 4; ++i) {
        uint4 qa = qp[i], ka = kp[i];
        sum += bflo(qa.x) * bflo(ka.x) + bfhi(qa.x) * bfhi(ka.x);
        sum += bflo(qa.y) * bflo(ka.y) + bfhi(qa.y) * bfhi(ka.y);
        sum += bflo(qa.z) * bflo(ka.z) + bfhi(qa.z) * bfhi(ka.z);
        sum += bflo(qa.w) * bflo(ka.w) + bfhi(qa.w) * bfhi(ka.w);
    }
    s_out[(size_t)p * 4 + hh] = sum * p4[hh] * INV_SQRT_D;
}

// ---- CSR segment softmax: 2 passes (max; exp+sum). 1/Z stored for agg. ----
__global__ __launch_bounds__(256) void csr_softmax(
    float* __restrict__ s, const int* __restrict__ rp, float* __restrict__ invZ)
{
    const int dst = blockIdx.x * 4 + (threadIdx.x >> 6);
    const int lane = threadIdx.x & 63;
    const int sub = lane >> 2, hh = lane & 3;
    int beg[3], end[3];
#pragma unroll
    for (int r = 0; r < 3; ++r) {
        beg[r] = rp[r * SCAN_L + dst];
        end[r] = rp[r * SCAN_L + dst + 1];
    }
    float m = -INFINITY;
#pragma unroll
    for (int r = 0; r < 3; ++r)
        for (int p = beg[r] + sub; p < end[r]; p += 16)
            m = fmaxf(m, s[((size_t)r * EE + p) * 4 + hh]);
#pragma unroll
    for (int st = 4; st < 64; st <<= 1) m = fmaxf(m, __shfl_xor(m, st));
    float zz = 0.f;
#pragma unroll
    for (int r = 0; r < 3; ++r)
        for (int p = beg[r] + sub; p < end[r]; p += 16) {
            size_t off = ((size_t)r * EE + p) * 4 + hh;
            float ex = expf(s[off] - m);
            s[off] = ex;
            zz += ex;
        }
#pragma unroll
    for (int st = 4; st < 64; st <<= 1) zz += __shfl_xor(zz, st);
    if (sub == 0) invZ[(size_t)dst * 4 + hh] = 1.f / (zz + 1e-16f);
}

// ---- agg_reg: wave-per-dst register aggregation of TRANSFORMED vt planes. ----
template<int NREL, int FIRST>
__global__ __launch_bounds__(256, 8) void agg_reg(
    const unsigned* __restrict__ pA, const unsigned* __restrict__ pB,
    const float* __restrict__ s, const int* __restrict__ rp,
    const int* __restrict__ csrc, int ra, int rb,
    const float* __restrict__ invZ, unsigned* __restrict__ As_g)
{
    const int dst = blockIdx.x * 4 + (threadIdx.x >> 6);
    const int lane = threadIdx.x & 63;
    const int hh = lane >> 4;
    float a0 = 0.f, a1 = 0.f;
#pragma unroll
    for (int q = 0; q < NREL; ++q) {
        const unsigned* pl = q ? pB : pA;
        const int r = q ? rb : ra;
        const int beg = rp[r * SCAN_L + dst];
        const int end = rp[r * SCAN_L + dst + 1];
        int p = beg;
        for (; p + 1 < end; p += 2) {       // 2 independent gathers in flight
            int s0 = csrc[r * EE + p];
            float al0 = s[((size_t)r * EE + p) * 4 + hh];
            int s1 = csrc[r * EE + p + 1];
            float al1 = s[((size_t)r * EE + p + 1) * 4 + hh];
            unsigned v0 = pl[(size_t)s0 * 64 + lane];
            unsigned v1 = pl[(size_t)s1 * 64 + lane];
            a0 += al0 * bflo(v0) + al1 * bflo(v1);
            a1 += al0 * bfhi(v0) + al1 * bfhi(v1);
        }
        if (p < end) {
            int s0 = csrc[r * EE + p];
            float al0 = s[((size_t)r * EE + p) * 4 + hh];
            unsigned v0 = pl[(size_t)s0 * 64 + lane];
            a0 += al0 * bflo(v0);
            a1 += al0 * bfhi(v0);
        }
    }
    float iz = invZ[(size_t)dst * 4 + hh];
    a0 *= iz; a1 *= iz;
    size_t off = (size_t)dst * 64 + lane;
    if (FIRST) {
        As_g[off] = bfpack(a0, a1);
    } else {
        unsigned old = As_g[off];
        As_g[off] = bfpack(bflo(old) + a0, bfhi(old) + a1);
    }
}

// ---- out_ln (MFMA core): gelu(As) @ Wout + bout -> skip -> LayerNorm -> h (bf16) ----
__global__ __launch_bounds__(256) void out_ln(
    const unsigned* __restrict__ As_g, unsigned* __restrict__ h_bf,
    const unsigned* __restrict__ WT, const float* __restrict__ bout,
    const float* __restrict__ skipp, const float* __restrict__ lg,
    const float* __restrict__ lb)
{
    __shared__ unsigned Asm[32 * 68];
    __shared__ unsigned Bsm[128 * 68];
    const int t = threadIdx.x;
    const int n0 = blockIdx.x * 32;
    for (int i = t; i < 32 * 64; i += 256) {
        int row = i >> 6, c2 = i & 63;
        unsigned u = As_g[(size_t)(n0 + row) * 64 + c2];
        Asm[row * 68 + c2] = bfpack(gelu_exact(bflo(u)), gelu_exact(bfhi(u)));
    }
    for (int i = t; i < 128 * 16; i += 256) {
        int row = i >> 4, q4 = i & 15;
        uint4 v = *(const uint4*)(WT + (size_t)row * 64 + q4 * 4);
        *(uint4*)&Bsm[row * 68 + q4 * 4] = v;
    }
    __syncthreads();
    const int w = t >> 6, lane = t & 63;
    const int m = lane & 15, quad = lane >> 4;
    const int tc0 = 2 * w;
    f32x4 acc00 = {0.f, 0.f, 0.f, 0.f}, acc01 = acc00, acc10 = acc00, acc11 = acc00;
    mfma_tile(Asm, Bsm, m, quad, tc0, acc00, acc01, acc10, acc11);
    __syncthreads();
    float* Cs = (float*)Bsm;
    mfma_epilogue(Cs, m, quad, tc0, acc00, acc01, acc10, acc11);
    __syncthreads();
    const int cg = t & 31;            // cols 4cg..4cg+3
    const int rg = (t >> 5) * 4;      // rows rg..rg+3
    float4 bv = *(const float4*)(bout + 4 * cg);
    const float alpha = 1.f / (1.f + expf(-skipp[0]));
    const float om = 1.f - alpha;
    float4 g4 = *(const float4*)(lg + 4 * cg);
    float4 b4 = *(const float4*)(lb + 4 * cg);
#pragma unroll
    for (int i = 0; i < 4; ++i) {
        const size_t n = (size_t)(n0 + rg + i);
        float4 cc = *(const float4*)(Cs + (rg + i) * 132 + 4 * cg);
        uint2 hu = *(const uint2*)(h_bf + n * 64 + 2 * cg);
        float o0 = alpha * (cc.x + bv.x) + om * bflo(hu.x);
        float o1 = alpha * (cc.y + bv.y) + om * bfhi(hu.x);
        float o2 = alpha * (cc.z + bv.z) + om * bflo(hu.y);
        float o3 = alpha * (cc.w + bv.w) + om * bfhi(hu.y);
        float sm = o0 + o1 + o2 + o3;
#pragma unroll
        for (int mm = 1; mm < 32; mm <<= 1) sm += __shfl_xor(sm, mm);
        float mu = sm * (1.f / 128.f);
        float d0 = o0 - mu, d1 = o1 - mu, d2 = o2 - mu, d3 = o3 - mu;
        float sq = d0 * d0 + d1 * d1 + d2 * d2 + d3 * d3;
#pragma unroll
        for (int mm = 1; mm < 32; mm <<= 1) sq += __shfl_xor(sq, mm);
        float rs = rsqrtf(sq * (1.f / 128.f) + 1e-5f);
        uint2 o = make_uint2(
            bfpack(d0 * rs * g4.x + b4.x, d1 * rs * g4.y + b4.y),
            bfpack(d2 * rs * g4.z + b4.z, d3 * rs * g4.w + b4.w));
        *(uint2*)(h_bf + n * 64 + 2 * cg) = o;
    }
}

// ---- pool_graph: 8 chunks per graph; every row in a block is the SAME graph
//      (batch sorted) -> pure register accumulation, one LDS reduce, 260
//      global atomics per block (vs 6.4M total in R13's run-flush version). ----
__global__ __launch_bounds__(256) void pool_graph(
    const unsigned* __restrict__ h_bf, const float* __restrict__ x,
    const int* __restrict__ batch, float* __restrict__ psum, float* __restrict__ pcnt)
{
    __shared__ float ls[258];     // [c2*4 + j] partials, + cw, cn
    const int b = blockIdx.x >> 3;
    const int chunk = blockIdx.x & 7;
    const int t = threadIdx.x;
    int lo = 0, hi = NN;
    while (lo < hi) { int mid = (lo + hi) >> 1; if (batch[mid] < b) lo = mid + 1; else hi = mid; }
    const int start = lo;
    lo = 0; hi = NN;
    while (lo < hi) { int mid = (lo + hi) >> 1; if (batch[mid] < b + 1) lo = mid + 1; else hi = mid; }
    const int end = lo;
    const int len = end - start;
    const int c0 = start + (int)(((long long)len * chunk) >> 3);
    const int c1 = start + (int)(((long long)len * (chunk + 1)) >> 3);
    for (int i = t; i < 258; i += 256) ls[i] = 0.f;
    __syncthreads();
    const int c2 = t & 63;            // col pair 2c2, 2c2+1
    const int rs = t >> 6;            // 4 row streams
    float sw0 = 0.f, sw1 = 0.f, sn0 = 0.f, sn1 = 0.f, cw = 0.f, cn = 0.f;
    for (int n = c0 + rs; n < c1; n += 4) {
        float w = (x[(size_t)n * 5 + 1] > 0.f) ? 1.f : 0.f;
        unsigned u = h_bf[(size_t)n * 64 + c2];
        float h0 = bflo(u), h1 = bfhi(u);
        sw0 += w * h0; sw1 += w * h1;
        sn0 += (1.f - w) * h0; sn1 += (1.f - w) * h1;
        cw += w; cn += 1.f - w;
    }
    atomicAdd(&ls[c2 * 4 + 0], sw0);
    atomicAdd(&ls[c2 * 4 + 1], sw1);
    atomicAdd(&ls[c2 * 4 + 2], sn0);
    atomicAdd(&ls[c2 * 4 + 3], sn1);
    if (c2 == 0) { atomicAdd(&ls[256], cw); atomicAdd(&ls[257], cn); }
    __syncthreads();
    if (t < 64) {
        atomicAdd(&psum[b * 256 + 2 * t],       ls[t * 4 + 0]);
        atomicAdd(&psum[b * 256 + 2 * t + 1],   ls[t * 4 + 1]);
        atomicAdd(&psum[b * 256 + 128 + 2 * t],     ls[t * 4 + 2]);
        atomicAdd(&psum[b * 256 + 128 + 2 * t + 1], ls[t * 4 + 3]);
    } else if (t == 64) {
        atomicAdd(&pcnt[b * 2], ls[256]);
        atomicAdd(&pcnt[b * 2 + 1], ls[257]);
    }
}

// ---------------- MLP head (pool finalize fused) ----------------
__global__ __launch_bounds__(256) void head_kernel(
    const float* __restrict__ psum, const float* __restrict__ pcnt,
    const float* __restrict__ task,
    const float* __restrict__ Wtf, const float* __restrict__ btf,
    const float* __restrict__ Wc1, const float* __restrict__ bc1,
    const float* __restrict__ Wc2, const float* __restrict__ bc2,
    float* __restrict__ out)
{
    __shared__ float in_s[640];
    __shared__ float ge_s[256];
    __shared__ float hc_s[64];
    const int b = blockIdx.x, t = threadIdx.x;
    if (t < 256) {
        float cnt = pcnt[b * 2 + (t >> 7)];
        float sv = psum[b * 256 + t];
        in_s[t] = (cnt > 0.f) ? sv / fmaxf(cnt, 1.f) : 0.f;
    }
    for (int i = t; i < 384; i += 256) in_s[256 + i] = task[b * 384 + i];
    __syncthreads();
    float acc = btf[t];
    for (int i = 0; i < 640; ++i) acc += in_s[i] * Wtf[i * 256 + t];
    ge_s[t] = fmaxf(acc, 0.f);
    __syncthreads();
    if (t < 64) {
        float a2 = bc1[t];
        for (int i = 0; i < 256; ++i) a2 += ge_s[i] * Wc1[i * 64 + t];
        hc_s[t] = fmaxf(a2, 0.f);
    }
    __syncthreads();
    if (t < 64) {
        float v = hc_s[t] * Wc2[t];
#pragma unroll
        for (int off = 32; off >= 1; off >>= 1) v += __shfl_down(v, off);
        if (t == 0) out[b] = v + bc2[0];
    }
}

__global__ __launch_bounds__(256) void zero_kernel(float4* __restrict__ p, int count4)
{
    int i = blockIdx.x * 256 + threadIdx.x;
    if (i < count4) p[i] = make_float4(0.f, 0.f, 0.f, 0.f);
}

extern "C" void kernel_launch(void* const* d_in, const int* in_sizes, int n_in,
                              void* d_out, int out_size, void* d_ws, size_t ws_size,
                              hipStream_t stream)
{
    const float* x      = (const float*)d_in[0];
    const int*   ast    = (const int*)d_in[1];
    const int*   batch  = (const int*)d_in[2];
    const int*   ei[3]  = {(const int*)d_in[3], (const int*)d_in[4], (const int*)d_in[5]};
    const float* task   = (const float*)d_in[6];
    const float* emb    = (const float*)d_in[7];
    const float* Win    = (const float*)d_in[8];
    const float* bin_   = (const float*)d_in[9];
    const float* Wkqv   = (const float*)d_in[10];
    const float* bkqv   = (const float*)d_in[11];
    const float* Wk_rel = (const float*)d_in[12];
    const float* Wv_rel = (const float*)d_in[13];
    const float* p_rel  = (const float*)d_in[14];
    const float* Wout   = (const float*)d_in[15];
    const float* bout   = (const float*)d_in[16];
    const float* skip   = (const float*)d_in[17];
    const float* ln_g   = (const float*)d_in[18];
    const float* ln_b   = (const float*)d_in[19];
    const float* Wtf    = (const float*)d_in[20];
    const float* btf    = (const float*)d_in[21];
    const float* Wc1    = (const float*)d_in[22];
    const float* bc1    = (const float*)d_in[23];
    const float* Wc2    = (const float*)d_in[24];
    const float* bc2    = (const float*)d_in[25];
    float* out = (float*)d_out;
    float* ws  = (float*)d_ws;

    unsigned* hB   = (unsigned*)(ws + OFF_HB);
    unsigned* P0   = (unsigned*)(ws + OFF_P0);   // q -> vt_0 -> vt_2
    unsigned* P1   = (unsigned*)(ws + OFF_P1);   // kt_r -> vt_1
    unsigned* AS   = (unsigned*)(ws + OFF_AS);
    float*    sbuf = ws + OFF_S;
    int*      rp   = (int*)(ws + OFF_RP);
    int*      csrc = (int*)(ws + OFF_CSRC);
    int*      cdst = (int*)(ws + OFF_CDST);
    int*      fill = (int*)(ws + OFF_P0);        // aliases P0 during CSR build only
    float*    Wf   = ws + OFF_WF;
    float*    bf   = ws + OFF_BF;
    int*      bs   = (int*)(ws + OFF_BS);
    float*    psum = ws + OFF_POOL;
    float*    pcnt = psum + (size_t)BB * 256;
    unsigned* WT   = (unsigned*)(ws + OFF_WT);   // 14 gemm slots + 2 Wout slots
    float*    invZ = ws + OFF_IZ;

    fold_weights<<<14, 256, 0, stream>>>(Wkqv, bkqv, Wk_rel, Wv_rel, Wf, bf);
    pack_wt<<<14, 256, 0, stream>>>(Wf, WT);
    pack_wt<<<2, 256, 0, stream>>>(Wout, WT + (size_t)14 * 8192);
    input_proj<<<NN / 16, 256, 0, stream>>>(x, ast, emb, Win, bin_, hB);

    zero_kernel<<<(600016 / 4 + 255) / 256, 256, 0, stream>>>((float4*)rp, 600016 / 4);
    zero_kernel<<<(600000 / 4 + 255) / 256, 256, 0, stream>>>((float4*)fill, 600000 / 4);
    csr_hist<<<(3 * EE + 255) / 256, 256, 0, stream>>>(ei[0], ei[1], ei[2], rp);
    scan1<<<dim3(SCAN_NB, 3), 256, 0, stream>>>(rp, bs);
    scan2<<<3, 128, 0, stream>>>(bs);
    scan3<<<dim3(SCAN_NB, 3), 256, 0, stream>>>(rp, bs);
    csr_scatter<<<(3 * EE + 255) / 256, 256, 0, stream>>>(
        ei[0], ei[1], ei[2], rp, fill, csrc, cdst);

    for (int l = 0; l < 2; ++l) {
        const size_t ls = (size_t)l * 7;   // slots: 0=q, 1..3=kt_r, 4..6=vt_r
        // q + kt_0 share one A-staging
        gemm_mfma2<<<NN / 32, 256, 0, stream>>>(
            hB, WT + ls * 8192, bf + ls * 128, P0,
            WT + (ls + 1) * 8192, bf + (ls + 1) * 128, P1);
        edge_scores_csr<<<(EE * 4 + 255) / 256, 256, 0, stream>>>(
            P0, P1, csrc, cdst, p_rel + (size_t)l * 12, sbuf);
        for (int r = 1; r < 3; ++r) {
            gemm_mfma<<<NN / 32, 256, 0, stream>>>(
                hB, WT + (ls + 1 + r) * 8192, bf + (ls + 1 + r) * 128, P1);
            edge_scores_csr<<<(EE * 4 + 255) / 256, 256, 0, stream>>>(
                P0, P1, csrc + (size_t)r * EE, cdst + (size_t)r * EE,
                p_rel + (size_t)(l * 3 + r) * 4, sbuf + (size_t)r * EE * 4);
        }
        csr_softmax<<<NN / 4, 256, 0, stream>>>(sbuf, rp, invZ);
        // phase B: q dead -> P0 = vt_0; kt dead -> P1 = vt_1; then P0 = vt_2
        gemm_mfma2<<<NN / 32, 256, 0, stream>>>(
            hB, WT + (ls + 4) * 8192, bf + (ls + 4) * 128, P0,
            WT + (ls + 5) * 8192, bf + (ls + 5) * 128, P1);
        agg_reg<2, 1><<<NN / 4, 256, 0, stream>>>(P0, P1, sbuf, rp, csrc, 0, 1, invZ, AS);
        gemm_mfma<<<NN / 32, 256, 0, stream>>>(hB, WT + (ls + 6) * 8192, bf + (ls + 6) * 128, P0);
        agg_reg<1, 0><<<NN / 4, 256, 0, stream>>>(P0, P0, sbuf, rp, csrc, 2, 2, invZ, AS);
        out_ln<<<NN / 32, 256, 0, stream>>>(
            AS, hB, WT + (size_t)(14 + l) * 8192, bout + (size_t)l * 128,
            skip + l, ln_g + (size_t)l * 128, ln_b + (size_t)l * 128);
    }

    zero_kernel<<<(16512 / 4 + 255) / 256, 256, 0, stream>>>((float4*)psum, 16512 / 4);
    pool_graph<<<BB * 8, 256, 0, stream>>>(hB, x, batch, psum, pcnt);
    head_kernel<<<BB, 256, 0, stream>>>(psum, pcnt, task, Wtf, btf, Wc1, bc1, Wc2, bc2, out);
}

// Round 15
// 1418.714 us; speedup vs baseline: 1.2351x; 1.0613x over previous
//
#include <hip/hip_runtime.h>
#include <math.h>

// Problem constants (match reference)
#define NN 200000
#define EE 300000
#define BB 64
#define INV_SQRT_D 0.17677669529663687f

// ---- workspace layout in 4-byte words. Total ≈ 58.39M words = 233.6 MB.
// ws budget is ~256MB-class (252 passed, 329 faulted) -> stay <= 252 MB.
#define OFF_HB   ((size_t)0)                    // [N][64] uint (bf16x2) node features
#define OFF_P0   ((size_t)12800000)             // [N][64] uint: q, then vt_0, then vt_2
#define OFF_P1   ((size_t)25600000)             // [N][64] uint: kt_r, then vt_1
#define OFF_AS   ((size_t)38400000)             // [N][64] uint: As accumulator (bf16)
#define OFF_S    ((size_t)51200000)             // [3][E][4] f32 scores -> exp (CSR order)
#define OFF_RP   ((size_t)54800000)             // [3][N+1] int rowptr (padded 600016)
#define OFF_CSRC ((size_t)55400016)             // [3][E] int src per CSR position
#define OFF_CDST ((size_t)56300016)             // [3][E] int dst per CSR position
#define OFF_WF   ((size_t)57200016)             // 14 x [128][128] f32 folded weights
#define OFF_BF   ((size_t)57429392)             // 14 x [128] f32 folded bias
#define OFF_BS   ((size_t)57431184)             // scan block sums 3*128 int
#define OFF_POOL ((size_t)57431568)             // psum [B][256] + pcnt [B][2] (16512)
#define OFF_WT   ((size_t)57448080)             // 16 x [128][64] uint packed W^T
#define OFF_IZ   ((size_t)57579152)             // [N][4] f32 softmax 1/Z
#define OFF_WIT  ((size_t)58379152)             // [128][52] uint packed Win^T (K padded 96->52 uints)

#define SCAN_L   (NN + 1)
#define SCAN_E   8
#define SCAN_EPB (256 * SCAN_E)                          // 2048
#define SCAN_NB  ((SCAN_L + SCAN_EPB - 1) / SCAN_EPB)    // 98

typedef __attribute__((ext_vector_type(8))) short bf16x8;
typedef __attribute__((ext_vector_type(4))) float f32x4;

__device__ __forceinline__ float gelu_exact(float v) {
    return 0.5f * v * (1.0f + erff(v * 0.70710678118654752f));
}
__device__ __forceinline__ float bflo(unsigned u) { return __uint_as_float(u << 16); }
__device__ __forceinline__ float bfhi(unsigned u) { return __uint_as_float(u & 0xffff0000u); }
__device__ __forceinline__ unsigned bfpack(float a, float b) {
    unsigned ua = __float_as_uint(a); ua += 0x7fffu + ((ua >> 16) & 1u);
    unsigned ub = __float_as_uint(b); ub += 0x7fffu + ((ub >> 16) & 1u);
    return (ua >> 16) | (ub & 0xffff0000u);
}

// ---- fold weights. 14 slots: per layer l: [l*7+0]=q copy, [l*7+1+r]=k@Wk_rel[r],
//      [l*7+4+r]=v@Wv_rel[r].  kqv split order is k|q|v (cols 0/128/256).
__global__ __launch_bounds__(256) void fold_weights(
    const float* __restrict__ Wkqv, const float* __restrict__ bkqv,
    const float* __restrict__ Wk_rel, const float* __restrict__ Wv_rel,
    float* __restrict__ Wf, float* __restrict__ bf)
{
    __shared__ float Wr[4096];
    const int b = blockIdx.x, t = threadIdx.x;
    const int l = b / 7, s = b % 7;
    const float* Wq = Wkqv + (size_t)l * 49152;   // [128][384]
    if (s == 0) {
        for (int i = t; i < 16384; i += 256) {
            int kk = i >> 7, c = i & 127;
            Wf[(size_t)b * 16384 + i] = Wq[kk * 384 + 128 + c];
        }
        if (t < 128) bf[b * 128 + t] = bkqv[l * 384 + 128 + t];
    } else {
        const int side = (s - 1) / 3, r = (s - 1) % 3;
        const int off = side ? 256 : 0;
        const float* Wrel = (side ? Wv_rel : Wk_rel) + (size_t)(l * 3 + r) * 4096;
        for (int i = t; i < 4096; i += 256) Wr[i] = Wrel[i];
        __syncthreads();
        for (int i = t; i < 16384; i += 256) {
            int kk = i >> 7, c = i & 127, hh = c >> 5, f = c & 31;
            const float* wrow = Wq + kk * 384 + off + hh * 32;
            const float* wr = Wr + hh * 1024 + f;
            float sum = 0.f;
#pragma unroll
            for (int d = 0; d < 32; ++d) sum += wrow[d] * wr[d * 32];
            Wf[(size_t)b * 16384 + i] = sum;
        }
        if (t < 128) {
            int hh = t >> 5, f = t & 31;
            float sum = 0.f;
#pragma unroll
            for (int d = 0; d < 32; ++d)
                sum += bkqv[l * 384 + off + hh * 32 + d] * Wr[hh * 1024 + d * 32 + f];
            bf[b * 128 + t] = sum;
        }
    }
}

// ---- pack W -> bf16x2-packed W^T: WT[slot][c][w] = (W[2w][c], W[2w+1][c]) ----
__global__ __launch_bounds__(256) void pack_wt(
    const float* __restrict__ W, unsigned* __restrict__ WT)
{
    const int slot = blockIdx.x, t = threadIdx.x;
    const float* Ws = W + (size_t)slot * 16384;
    unsigned* WTs = WT + (size_t)slot * 8192;
    for (int i = t; i < 8192; i += 256) {
        int c = i >> 6, w = i & 63;
        WTs[i] = bfpack(Ws[(size_t)(2 * w) * 128 + c], Ws[(size_t)(2 * w + 1) * 128 + c]);
    }
}

// ---- pack Win (69x128 f32) -> WinT bf16 [128][52] (K padded to 96 = 48 uints + 4 pad) ----
__global__ __launch_bounds__(256) void pack_win(
    const float* __restrict__ Win, unsigned* __restrict__ WinT)
{
    const int t = threadIdx.x;
    for (int i = t; i < 128 * 52; i += 256) {
        int c = i / 52, u = i - c * 52;
        unsigned v = 0;
        if (u < 34) {
            v = bfpack(Win[(size_t)(2 * u) * 128 + c], Win[(size_t)(2 * u + 1) * 128 + c]);
        } else if (u == 34) {
            v = bfpack(Win[(size_t)68 * 128 + c], 0.f);
        }
        WinT[i] = v;
    }
}

// ---- MFMA input projection: h_bf = bf16([emb[ast], x] @ Win + bin), K=96 padded ----
__global__ __launch_bounds__(256) void input_proj_mfma(
    const float* __restrict__ x, const int* __restrict__ ast,
    const float* __restrict__ emb, const unsigned* __restrict__ WinT,
    const float* __restrict__ bin_, unsigned* __restrict__ h_bf)
{
    __shared__ unsigned Asm[32 * 52];    // 6656 B
    __shared__ unsigned Bsm[128 * 52];   // 26624 B
    const int t = threadIdx.x;
    const int n0 = blockIdx.x * 32;
    // stage A (bf16): cols 0..63 = emb[ast[n]], 64..68 = x[n], 69..95 = 0
    for (int i = t; i < 32 * 64; i += 256) {
        int row = i >> 6, u = i & 63;
        if (u < 52) {
            int n = n0 + row;
            unsigned v = 0;
            if (u < 32) {
                const float* er = emb + (size_t)ast[n] * 64 + 2 * u;
                v = bfpack(er[0], er[1]);
            } else if (u == 32) {
                v = bfpack(x[(size_t)n * 5], x[(size_t)n * 5 + 1]);
            } else if (u == 33) {
                v = bfpack(x[(size_t)n * 5 + 2], x[(size_t)n * 5 + 3]);
            } else if (u == 34) {
                v = bfpack(x[(size_t)n * 5 + 4], 0.f);
            }
            Asm[row * 52 + u] = v;
        }
    }
    for (int i = t; i < 128 * 13; i += 256) {
        int row = i / 13, q4 = i - row * 13;
        uint4 v = *(const uint4*)(WinT + (size_t)row * 52 + q4 * 4);
        *(uint4*)&Bsm[row * 52 + q4 * 4] = v;
    }
    __syncthreads();
    const int w = t >> 6, lane = t & 63;
    const int m = lane & 15, quad = lane >> 4;
    const int tc0 = 2 * w;
    f32x4 acc00 = {0.f, 0.f, 0.f, 0.f}, acc01 = acc00, acc10 = acc00, acc11 = acc00;
#pragma unroll
    for (int kc = 0; kc < 3; ++kc) {
        const int koff = kc * 16 + quad * 4;
        bf16x8 a0 = *(const bf16x8*)&Asm[m * 52 + koff];
        bf16x8 a1 = *(const bf16x8*)&Asm[(16 + m) * 52 + koff];
        bf16x8 b0 = *(const bf16x8*)&Bsm[(tc0 * 16 + m) * 52 + koff];
        bf16x8 b1 = *(const bf16x8*)&Bsm[((tc0 + 1) * 16 + m) * 52 + koff];
        acc00 = __builtin_amdgcn_mfma_f32_16x16x32_bf16(a0, b0, acc00, 0, 0, 0);
        acc01 = __builtin_amdgcn_mfma_f32_16x16x32_bf16(a0, b1, acc01, 0, 0, 0);
        acc10 = __builtin_amdgcn_mfma_f32_16x16x32_bf16(a1, b0, acc10, 0, 0, 0);
        acc11 = __builtin_amdgcn_mfma_f32_16x16x32_bf16(a1, b1, acc11, 0, 0, 0);
    }
    __syncthreads();
    float* Cs = (float*)Bsm;             // [32][132]
#pragma unroll
    for (int r = 0; r < 4; ++r) {
        Cs[(quad * 4 + r) * 132 + tc0 * 16 + m]            = acc00[r];
        Cs[(quad * 4 + r) * 132 + (tc0 + 1) * 16 + m]      = acc01[r];
        Cs[(16 + quad * 4 + r) * 132 + tc0 * 16 + m]       = acc10[r];
        Cs[(16 + quad * 4 + r) * 132 + (tc0 + 1) * 16 + m] = acc11[r];
    }
    __syncthreads();
    for (int i = t; i < 32 * 64; i += 256) {
        int row = i >> 6, c2 = i & 63;
        float c0 = Cs[row * 132 + 2 * c2]     + bin_[2 * c2];
        float c1 = Cs[row * 132 + 2 * c2 + 1] + bin_[2 * c2 + 1];
        h_bf[(size_t)(n0 + row) * 64 + c2] = bfpack(c0, c1);
    }
}

// ---- CSR build: histogram -> scan -> scatter ----
__global__ __launch_bounds__(256) void csr_hist(
    const int* __restrict__ ei0, const int* __restrict__ ei1, const int* __restrict__ ei2,
    int* __restrict__ rp)
{
    int idx = blockIdx.x * 256 + threadIdx.x;
    if (idx >= 3 * EE) return;
    int r = idx / EE, e = idx - r * EE;
    const int* ei = (r == 0) ? ei0 : ((r == 1) ? ei1 : ei2);
    atomicAdd(&rp[r * SCAN_L + ei[EE + e] + 1], 1);
}

__global__ __launch_bounds__(256) void scan1(int* __restrict__ rp, int* __restrict__ bs)
{
    __shared__ int ts[256];
    const int r = blockIdx.y;
    int* a = rp + (size_t)r * SCAN_L;
    const int base = blockIdx.x * SCAN_EPB + threadIdx.x * SCAN_E;
    int v[SCAN_E];
    int tot = 0;
#pragma unroll
    for (int j = 0; j < SCAN_E; ++j) {
        int idx = base + j;
        v[j] = (idx < SCAN_L) ? a[idx] : 0;
        tot += v[j];
    }
    ts[threadIdx.x] = tot;
    __syncthreads();
    for (int st = 1; st < 256; st <<= 1) {
        int add = (threadIdx.x >= st) ? ts[threadIdx.x - st] : 0;
        __syncthreads();
        ts[threadIdx.x] += add;
        __syncthreads();
    }
    int run = ts[threadIdx.x] - tot;
#pragma unroll
    for (int j = 0; j < SCAN_E; ++j) {
        run += v[j];
        int idx = base + j;
        if (idx < SCAN_L) a[idx] = run;
    }
    if (threadIdx.x == 255) bs[r * 128 + blockIdx.x] = ts[255];
}

__global__ __launch_bounds__(128) void scan2(int* __restrict__ bs)
{
    __shared__ int ts[128];
    const int r = blockIdx.x, t = threadIdx.x;
    int v = (t < SCAN_NB) ? bs[r * 128 + t] : 0;
    ts[t] = v;
    __syncthreads();
    for (int st = 1; st < 128; st <<= 1) {
        int add = (t >= st) ? ts[t - st] : 0;
        __syncthreads();
        ts[t] += add;
        __syncthreads();
    }
    bs[r * 128 + t] = ts[t];
}

__global__ __launch_bounds__(256) void scan3(int* __restrict__ rp, const int* __restrict__ bs)
{
    const int r = blockIdx.y;
    if (blockIdx.x == 0) return;
    const int off = bs[r * 128 + blockIdx.x - 1];
    const int base = blockIdx.x * SCAN_EPB + threadIdx.x * SCAN_E;
    int* a = rp + (size_t)r * SCAN_L;
#pragma unroll
    for (int j = 0; j < SCAN_E; ++j) {
        int idx = base + j;
        if (idx < SCAN_L) a[idx] += off;
    }
}

__global__ __launch_bounds__(256) void csr_scatter(
    const int* __restrict__ ei0, const int* __restrict__ ei1, const int* __restrict__ ei2,
    const int* __restrict__ rp, int* __restrict__ fill,
    int* __restrict__ csrc, int* __restrict__ cdst)
{
    int idx = blockIdx.x * 256 + threadIdx.x;
    if (idx >= 3 * EE) return;
    int r = idx / EE, e = idx - r * EE;
    const int* ei = (r == 0) ? ei0 : ((r == 1) ? ei1 : ei2);
    int src = ei[e], dst = ei[EE + e];
    int pos = rp[r * SCAN_L + dst] + atomicAdd(&fill[r * NN + dst], 1);
    csrc[r * EE + pos] = src;
    cdst[r * EE + pos] = dst;
}

// ---- 64-row MFMA GEMM core: per wave 4 row-tiles x 2 col-tiles, 32 MFMA ----
__device__ __forceinline__ void mfma_tile64(
    const unsigned* Asm, const unsigned* Bsm, int m, int quad, int tc0, f32x4 acc[4][2])
{
#pragma unroll
    for (int kc = 0; kc < 4; ++kc) {
        const int koff = kc * 16 + quad * 4;
        bf16x8 b0 = *(const bf16x8*)&Bsm[(tc0 * 16 + m) * 68 + koff];
        bf16x8 b1 = *(const bf16x8*)&Bsm[((tc0 + 1) * 16 + m) * 68 + koff];
#pragma unroll
        for (int rt = 0; rt < 4; ++rt) {
            bf16x8 a = *(const bf16x8*)&Asm[(rt * 16 + m) * 68 + koff];
            acc[rt][0] = __builtin_amdgcn_mfma_f32_16x16x32_bf16(a, b0, acc[rt][0], 0, 0, 0);
            acc[rt][1] = __builtin_amdgcn_mfma_f32_16x16x32_bf16(a, b1, acc[rt][1], 0, 0, 0);
        }
    }
}

__device__ __forceinline__ void mfma_epi64(
    float* Cs, int m, int quad, int tc0, const f32x4 acc[4][2])
{
#pragma unroll
    for (int rt = 0; rt < 4; ++rt)
#pragma unroll
        for (int r = 0; r < 4; ++r) {
            Cs[(rt * 16 + quad * 4 + r) * 132 + tc0 * 16 + m]       = acc[rt][0][r];
            Cs[(rt * 16 + quad * 4 + r) * 132 + (tc0 + 1) * 16 + m] = acc[rt][1][r];
        }
}

// ---- 1-slot 64-row MFMA GEMM ----
__global__ __launch_bounds__(256, 4) void gemm_mfma(
    const unsigned* __restrict__ in_bf, const unsigned* __restrict__ WT,
    const float* __restrict__ bias, unsigned* __restrict__ outp)
{
    __shared__ unsigned Asm[64 * 68];    // 17408 B
    __shared__ unsigned Bsm[128 * 68];   // 34816 B
    const int t = threadIdx.x;
    const int n0 = blockIdx.x * 64;
    for (int i = t; i < 64 * 16; i += 256) {
        int row = i >> 4, q4 = i & 15;
        uint4 v = *(const uint4*)(in_bf + (size_t)(n0 + row) * 64 + q4 * 4);
        *(uint4*)&Asm[row * 68 + q4 * 4] = v;
    }
    for (int i = t; i < 128 * 16; i += 256) {
        int row = i >> 4, q4 = i & 15;
        uint4 v = *(const uint4*)(WT + (size_t)row * 64 + q4 * 4);
        *(uint4*)&Bsm[row * 68 + q4 * 4] = v;
    }
    __syncthreads();
    const int w = t >> 6, lane = t & 63;
    const int m = lane & 15, quad = lane >> 4;
    const int tc0 = 2 * w;
    f32x4 acc[4][2];
#pragma unroll
    for (int rt = 0; rt < 4; ++rt) { acc[rt][0] = (f32x4){0.f,0.f,0.f,0.f}; acc[rt][1] = acc[rt][0]; }
    mfma_tile64(Asm, Bsm, m, quad, tc0, acc);
    __syncthreads();
    float* Cs = (float*)Bsm;             // [64][132] = 33792 B
    mfma_epi64(Cs, m, quad, tc0, acc);
    __syncthreads();
    for (int i = t; i < 64 * 64; i += 256) {
        int row = i >> 6, c2 = i & 63;
        float c0 = Cs[row * 132 + 2 * c2]     + bias[2 * c2];
        float c1 = Cs[row * 132 + 2 * c2 + 1] + bias[2 * c2 + 1];
        outp[(size_t)(n0 + row) * 64 + c2] = bfpack(c0, c1);
    }
}

// ---- 2-slot 64-row MFMA GEMM: A staged once ----
__global__ __launch_bounds__(256, 4) void gemm_mfma2(
    const unsigned* __restrict__ in_bf,
    const unsigned* __restrict__ WT0, const float* __restrict__ bias0,
    unsigned* __restrict__ out0,
    const unsigned* __restrict__ WT1, const float* __restrict__ bias1,
    unsigned* __restrict__ out1)
{
    __shared__ unsigned Asm[64 * 68];
    __shared__ unsigned Bsm[128 * 68];
    const int t = threadIdx.x;
    const int n0 = blockIdx.x * 64;
    const int w = t >> 6, lane = t & 63;
    const int m = lane & 15, quad = lane >> 4;
    const int tc0 = 2 * w;
    for (int i = t; i < 64 * 16; i += 256) {
        int row = i >> 4, q4 = i & 15;
        uint4 v = *(const uint4*)(in_bf + (size_t)(n0 + row) * 64 + q4 * 4);
        *(uint4*)&Asm[row * 68 + q4 * 4] = v;
    }
#pragma unroll
    for (int sl = 0; sl < 2; ++sl) {
        const unsigned* WT = sl ? WT1 : WT0;
        const float* bias = sl ? bias1 : bias0;
        unsigned* outp = sl ? out1 : out0;
        __syncthreads();
        for (int i = t; i < 128 * 16; i += 256) {
            int row = i >> 4, q4 = i & 15;
            uint4 v = *(const uint4*)(WT + (size_t)row * 64 + q4 * 4);
            *(uint4*)&Bsm[row * 68 + q4 * 4] = v;
        }
        __syncthreads();
        f32x4 acc[4][2];
#pragma unroll
        for (int rt = 0; rt < 4; ++rt) { acc[rt][0] = (f32x4){0.f,0.f,0.f,0.f}; acc[rt][1] = acc[rt][0]; }
        mfma_tile64(Asm, Bsm, m, quad, tc0, acc);
        __syncthreads();
        float* Cs = (float*)Bsm;
        mfma_epi64(Cs, m, quad, tc0, acc);
        __syncthreads();
        for (int i = t; i < 64 * 64; i += 256) {
            int row = i >> 6, c2 = i & 63;
            float c0 = Cs[row * 132 + 2 * c2]     + bias[2 * c2];
            float c1 = Cs[row * 132 + 2 * c2 + 1] + bias[2 * c2 + 1];
            outp[(size_t)(n0 + row) * 64 + c2] = bfpack(c0, c1);
        }
    }
}

// ---- edge scores in CSR position order ----
__global__ __launch_bounds__(256) void edge_scores_csr(
    const unsigned* __restrict__ q_bf, const unsigned* __restrict__ k_bf,
    const int* __restrict__ csrc, const int* __restrict__ cdst,
    const float* __restrict__ p4, float* __restrict__ s_out)
{
    int idx = blockIdx.x * 256 + threadIdx.x;
    if (idx >= EE * 4) return;
    int p = idx >> 2, hh = idx & 3;
    int src = csrc[p], dst = cdst[p];
    const uint4* qp = (const uint4*)(q_bf + (size_t)dst * 64 + hh * 16);
    const uint4* kp = (const uint4*)(k_bf + (size_t)src * 64 + hh * 16);
    float sum = 0.f;
#pragma unroll
    for (int i = 0; i < 4; ++i) {
        uint4 qa = qp[i], ka = kp[i];
        sum += bflo(qa.x) * bflo(ka.x) + bfhi(qa.x) * bfhi(ka.x);
        sum += bflo(qa.y) * bflo(ka.y) + bfhi(qa.y) * bfhi(ka.y);
        sum += bflo(qa.z) * bflo(ka.z) + bfhi(qa.z) * bfhi(ka.z);
        sum += bflo(qa.w) * bflo(ka.w) + bfhi(qa.w) * bfhi(ka.w);
    }
    s_out[(size_t)p * 4 + hh] = sum * p4[hh] * INV_SQRT_D;
}

// ---- CSR segment softmax: 2 passes (max; exp+sum). 1/Z stored for agg. ----
__global__ __launch_bounds__(256) void csr_softmax(
    float* __restrict__ s, const int* __restrict__ rp, float* __restrict__ invZ)
{
    const int dst = blockIdx.x * 4 + (threadIdx.x >> 6);
    const int lane = threadIdx.x & 63;
    const int sub = lane >> 2, hh = lane & 3;
    int beg[3], end[3];
#pragma unroll
    for (int r = 0; r < 3; ++r) {
        beg[r] = rp[r * SCAN_L + dst];
        end[r] = rp[r * SCAN_L + dst + 1];
    }
    float m = -INFINITY;
#pragma unroll
    for (int r = 0; r < 3; ++r)
        for (int p = beg[r] + sub; p < end[r]; p += 16)
            m = fmaxf(m, s[((size_t)r * EE + p) * 4 + hh]);
#pragma unroll
    for (int st = 4; st < 64; st <<= 1) m = fmaxf(m, __shfl_xor(m, st));
    float zz = 0.f;
#pragma unroll
    for (int r = 0; r < 3; ++r)
        for (int p = beg[r] + sub; p < end[r]; p += 16) {
            size_t off = ((size_t)r * EE + p) * 4 + hh;
            float ex = expf(s[off] - m);
            s[off] = ex;
            zz += ex;
        }
#pragma unroll
    for (int st = 4; st < 64; st <<= 1) zz += __shfl_xor(zz, st);
    if (sub == 0) invZ[(size_t)dst * 4 + hh] = 1.f / (zz + 1e-16f);
}

// ---- agg_reg: wave-per-dst register aggregation of TRANSFORMED vt planes. ----
template<int NREL, int FIRST>
__global__ __launch_bounds__(256, 8) void agg_reg(
    const unsigned* __restrict__ pA, const unsigned* __restrict__ pB,
    const float* __restrict__ s, const int* __restrict__ rp,
    const int* __restrict__ csrc, int ra, int rb,
    const float* __restrict__ invZ, unsigned* __restrict__ As_g)
{
    const int dst = blockIdx.x * 4 + (threadIdx.x >> 6);
    const int lane = threadIdx.x & 63;
    const int hh = lane >> 4;
    float a0 = 0.f, a1 = 0.f;
#pragma unroll
    for (int q = 0; q < NREL; ++q) {
        const unsigned* pl = q ? pB : pA;
        const int r = q ? rb : ra;
        const int beg = rp[r * SCAN_L + dst];
        const int end = rp[r * SCAN_L + dst + 1];
        int p = beg;
        for (; p + 1 < end; p += 2) {
            int s0 = csrc[r * EE + p];
            float al0 = s[((size_t)r * EE + p) * 4 + hh];
            int s1 = csrc[r * EE + p + 1];
            float al1 = s[((size_t)r * EE + p + 1) * 4 + hh];
            unsigned v0 = pl[(size_t)s0 * 64 + lane];
            unsigned v1 = pl[(size_t)s1 * 64 + lane];
            a0 += al0 * bflo(v0) + al1 * bflo(v1);
            a1 += al0 * bfhi(v0) + al1 * bfhi(v1);
        }
        if (p < end) {
            int s0 = csrc[r * EE + p];
            float al0 = s[((size_t)r * EE + p) * 4 + hh];
            unsigned v0 = pl[(size_t)s0 * 64 + lane];
            a0 += al0 * bflo(v0);
            a1 += al0 * bfhi(v0);
        }
    }
    float iz = invZ[(size_t)dst * 4 + hh];
    a0 *= iz; a1 *= iz;
    size_t off = (size_t)dst * 64 + lane;
    if (FIRST) {
        As_g[off] = bfpack(a0, a1);
    } else {
        unsigned old = As_g[off];
        As_g[off] = bfpack(bflo(old) + a0, bfhi(old) + a1);
    }
}

// ---- out_ln (MFMA core, 32 rows): gelu(As) @ Wout + bout -> skip -> LN -> h ----
__global__ __launch_bounds__(256) void out_ln(
    const unsigned* __restrict__ As_g, unsigned* __restrict__ h_bf,
    const unsigned* __restrict__ WT, const float* __restrict__ bout,
    const float* __restrict__ skipp, const float* __restrict__ lg,
    const float* __restrict__ lb)
{
    __shared__ unsigned Asm[32 * 68];
    __shared__ unsigned Bsm[128 * 68];
    const int t = threadIdx.x;
    const int n0 = blockIdx.x * 32;
    for (int i = t; i < 32 * 64; i += 256) {
        int row = i >> 6, c2 = i & 63;
        unsigned u = As_g[(size_t)(n0 + row) * 64 + c2];
        Asm[row * 68 + c2] = bfpack(gelu_exact(bflo(u)), gelu_exact(bfhi(u)));
    }
    for (int i = t; i < 128 * 16; i += 256) {
        int row = i >> 4, q4 = i & 15;
        uint4 v = *(const uint4*)(WT + (size_t)row * 64 + q4 * 4);
        *(uint4*)&Bsm[row * 68 + q4 * 4] = v;
    }
    __syncthreads();
    const int w = t >> 6, lane = t & 63;
    const int m = lane & 15, quad = lane >> 4;
    const int tc0 = 2 * w;
    f32x4 acc00 = {0.f, 0.f, 0.f, 0.f}, acc01 = acc00, acc10 = acc00, acc11 = acc00;
#pragma unroll
    for (int kc = 0; kc < 4; ++kc) {
        const int koff = kc * 16 + quad * 4;
        bf16x8 a0 = *(const bf16x8*)&Asm[m * 68 + koff];
        bf16x8 a1 = *(const bf16x8*)&Asm[(16 + m) * 68 + koff];
        bf16x8 b0 = *(const bf16x8*)&Bsm[(tc0 * 16 + m) * 68 + koff];
        bf16x8 b1 = *(const bf16x8*)&Bsm[((tc0 + 1) * 16 + m) * 68 + koff];
        acc00 = __builtin_amdgcn_mfma_f32_16x16x32_bf16(a0, b0, acc00, 0, 0, 0);
        acc01 = __builtin_amdgcn_mfma_f32_16x16x32_bf16(a0, b1, acc01, 0, 0, 0);
        acc10 = __builtin_amdgcn_mfma_f32_16x16x32_bf16(a1, b0, acc10, 0, 0, 0);
        acc11 = __builtin_amdgcn_mfma_f32_16x16x32_bf16(a1, b1, acc11, 0, 0, 0);
    }
    __syncthreads();
    float* Cs = (float*)Bsm;
#pragma unroll
    for (int r = 0; r < 4; ++r) {
        Cs[(quad * 4 + r) * 132 + tc0 * 16 + m]            = acc00[r];
        Cs[(quad * 4 + r) * 132 + (tc0 + 1) * 16 + m]      = acc01[r];
        Cs[(16 + quad * 4 + r) * 132 + tc0 * 16 + m]       = acc10[r];
        Cs[(16 + quad * 4 + r) * 132 + (tc0 + 1) * 16 + m] = acc11[r];
    }
    __syncthreads();
    const int cg = t & 31;
    const int rg = (t >> 5) * 4;
    float4 bv = *(const float4*)(bout + 4 * cg);
    const float alpha = 1.f / (1.f + expf(-skipp[0]));
    const float om = 1.f - alpha;
    float4 g4 = *(const float4*)(lg + 4 * cg);
    float4 b4 = *(const float4*)(lb + 4 * cg);
#pragma unroll
    for (int i = 0; i < 4; ++i) {
        const size_t n = (size_t)(n0 + rg + i);
        float4 cc = *(const float4*)(Cs + (rg + i) * 132 + 4 * cg);
        uint2 hu = *(const uint2*)(h_bf + n * 64 + 2 * cg);
        float o0 = alpha * (cc.x + bv.x) + om * bflo(hu.x);
        float o1 = alpha * (cc.y + bv.y) + om * bfhi(hu.x);
        float o2 = alpha * (cc.z + bv.z) + om * bflo(hu.y);
        float o3 = alpha * (cc.w + bv.w) + om * bfhi(hu.y);
        float sm = o0 + o1 + o2 + o3;
#pragma unroll
        for (int mm = 1; mm < 32; mm <<= 1) sm += __shfl_xor(sm, mm);
        float mu = sm * (1.f / 128.f);
        float d0 = o0 - mu, d1 = o1 - mu, d2 = o2 - mu, d3 = o3 - mu;
        float sq = d0 * d0 + d1 * d1 + d2 * d2 + d3 * d3;
#pragma unroll
        for (int mm = 1; mm < 32; mm <<= 1) sq += __shfl_xor(sq, mm);
        float rs = rsqrtf(sq * (1.f / 128.f) + 1e-5f);
        uint2 o = make_uint2(
            bfpack(d0 * rs * g4.x + b4.x, d1 * rs * g4.y + b4.y),
            bfpack(d2 * rs * g4.z + b4.z, d3 * rs * g4.w + b4.w));
        *(uint2*)(h_bf + n * 64 + 2 * cg) = o;
    }
}

// ---- pool_graph: 8 chunks/graph; single-graph blocks -> register accumulate,
//      LDS reduce, 260 global atomics per block ----
__global__ __launch_bounds__(256) void pool_graph(
    const unsigned* __restrict__ h_bf, const float* __restrict__ x,
    const int* __restrict__ batch, float* __restrict__ psum, float* __restrict__ pcnt)
{
    __shared__ float ls[258];
    const int b = blockIdx.x >> 3;
    const int chunk = blockIdx.x & 7;
    const int t = threadIdx.x;
    int lo = 0, hi = NN;
    while (lo < hi) { int mid = (lo + hi) >> 1; if (batch[mid] < b) lo = mid + 1; else hi = mid; }
    const int start = lo;
    lo = 0; hi = NN;
    while (lo < hi) { int mid = (lo + hi) >> 1; if (batch[mid] < b + 1) lo = mid + 1; else hi = mid; }
    const int end = lo;
    const int len = end - start;
    const int c0 = start + (int)(((long long)len * chunk) >> 3);
    const int c1 = start + (int)(((long long)len * (chunk + 1)) >> 3);
    for (int i = t; i < 258; i += 256) ls[i] = 0.f;
    __syncthreads();
    const int c2 = t & 63;
    const int rs = t >> 6;
    float sw0 = 0.f, sw1 = 0.f, sn0 = 0.f, sn1 = 0.f, cw = 0.f, cn = 0.f;
    for (int n = c0 + rs; n < c1; n += 4) {
        float w = (x[(size_t)n * 5 + 1] > 0.f) ? 1.f : 0.f;
        unsigned u = h_bf[(size_t)n * 64 + c2];
        float h0 = bflo(u), h1 = bfhi(u);
        sw0 += w * h0; sw1 += w * h1;
        sn0 += (1.f - w) * h0; sn1 += (1.f - w) * h1;
        cw += w; cn += 1.f - w;
    }
    atomicAdd(&ls[c2 * 4 + 0], sw0);
    atomicAdd(&ls[c2 * 4 + 1], sw1);
    atomicAdd(&ls[c2 * 4 + 2], sn0);
    atomicAdd(&ls[c2 * 4 + 3], sn1);
    if (c2 == 0) { atomicAdd(&ls[256], cw); atomicAdd(&ls[257], cn); }
    __syncthreads();
    if (t < 64) {
        atomicAdd(&psum[b * 256 + 2 * t],       ls[t * 4 + 0]);
        atomicAdd(&psum[b * 256 + 2 * t + 1],   ls[t * 4 + 1]);
        atomicAdd(&psum[b * 256 + 128 + 2 * t],     ls[t * 4 + 2]);
        atomicAdd(&psum[b * 256 + 128 + 2 * t + 1], ls[t * 4 + 3]);
    } else if (t == 64) {
        atomicAdd(&pcnt[b * 2], ls[256]);
        atomicAdd(&pcnt[b * 2 + 1], ls[257]);
    }
}

// ---------------- MLP head (pool finalize fused) ----------------
__global__ __launch_bounds__(256) void head_kernel(
    const float* __restrict__ psum, const float* __restrict__ pcnt,
    const float* __restrict__ task,
    const float* __restrict__ Wtf, const float* __restrict__ btf,
    const float* __restrict__ Wc1, const float* __restrict__ bc1,
    const float* __restrict__ Wc2, const float* __restrict__ bc2,
    float* __restrict__ out)
{
    __shared__ float in_s[640];
    __shared__ float ge_s[256];
    __shared__ float hc_s[64];
    const int b = blockIdx.x, t = threadIdx.x;
    if (t < 256) {
        float cnt = pcnt[b * 2 + (t >> 7)];
        float sv = psum[b * 256 + t];
        in_s[t] = (cnt > 0.f) ? sv / fmaxf(cnt, 1.f) : 0.f;
    }
    for (int i = t; i < 384; i += 256) in_s[256 + i] = task[b * 384 + i];
    __syncthreads();
    float acc = btf[t];
    for (int i = 0; i < 640; ++i) acc += in_s[i] * Wtf[i * 256 + t];
    ge_s[t] = fmaxf(acc, 0.f);
    __syncthreads();
    if (t < 64) {
        float a2 = bc1[t];
        for (int i = 0; i < 256; ++i) a2 += ge_s[i] * Wc1[i * 64 + t];
        hc_s[t] = fmaxf(a2, 0.f);
    }
    __syncthreads();
    if (t < 64) {
        float v = hc_s[t] * Wc2[t];
#pragma unroll
        for (int off = 32; off >= 1; off >>= 1) v += __shfl_down(v, off);
        if (t == 0) out[b] = v + bc2[0];
    }
}

__global__ __launch_bounds__(256) void zero_kernel(float4* __restrict__ p, int count4)
{
    int i = blockIdx.x * 256 + threadIdx.x;
    if (i < count4) p[i] = make_float4(0.f, 0.f, 0.f, 0.f);
}

extern "C" void kernel_launch(void* const* d_in, const int* in_sizes, int n_in,
                              void* d_out, int out_size, void* d_ws, size_t ws_size,
                              hipStream_t stream)
{
    const float* x      = (const float*)d_in[0];
    const int*   ast    = (const int*)d_in[1];
    const int*   batch  = (const int*)d_in[2];
    const int*   ei[3]  = {(const int*)d_in[3], (const int*)d_in[4], (const int*)d_in[5]};
    const float* task   = (const float*)d_in[6];
    const float* emb    = (const float*)d_in[7];
    const float* Win    = (const float*)d_in[8];
    const float* bin_   = (const float*)d_in[9];
    const float* Wkqv   = (const float*)d_in[10];
    const float* bkqv   = (const float*)d_in[11];
    const float* Wk_rel = (const float*)d_in[12];
    const float* Wv_rel = (const float*)d_in[13];
    const float* p_rel  = (const float*)d_in[14];
    const float* Wout   = (const float*)d_in[15];
    const float* bout   = (const float*)d_in[16];
    const float* skip   = (const float*)d_in[17];
    const float* ln_g   = (const float*)d_in[18];
    const float* ln_b   = (const float*)d_in[19];
    const float* Wtf    = (const float*)d_in[20];
    const float* btf    = (const float*)d_in[21];
    const float* Wc1    = (const float*)d_in[22];
    const float* bc1    = (const float*)d_in[23];
    const float* Wc2    = (const float*)d_in[24];
    const float* bc2    = (const float*)d_in[25];
    float* out = (float*)d_out;
    float* ws  = (float*)d_ws;

    unsigned* hB   = (unsigned*)(ws + OFF_HB);
    unsigned* P0   = (unsigned*)(ws + OFF_P0);   // q -> vt_0 -> vt_2
    unsigned* P1   = (unsigned*)(ws + OFF_P1);   // kt_r -> vt_1
    unsigned* AS   = (unsigned*)(ws + OFF_AS);
    float*    sbuf = ws + OFF_S;
    int*      rp   = (int*)(ws + OFF_RP);
    int*      csrc = (int*)(ws + OFF_CSRC);
    int*      cdst = (int*)(ws + OFF_CDST);
    int*      fill = (int*)(ws + OFF_P0);        // aliases P0 during CSR build only
    float*    Wf   = ws + OFF_WF;
    float*    bf   = ws + OFF_BF;
    int*      bs   = (int*)(ws + OFF_BS);
    float*    psum = ws + OFF_POOL;
    float*    pcnt = psum + (size_t)BB * 256;
    unsigned* WT   = (unsigned*)(ws + OFF_WT);   // 14 gemm slots + 2 Wout slots
    float*    invZ = ws + OFF_IZ;
    unsigned* WinT = (unsigned*)(ws + OFF_WIT);

    fold_weights<<<14, 256, 0, stream>>>(Wkqv, bkqv, Wk_rel, Wv_rel, Wf, bf);
    pack_wt<<<14, 256, 0, stream>>>(Wf, WT);
    pack_wt<<<2, 256, 0, stream>>>(Wout, WT + (size_t)14 * 8192);
    pack_win<<<1, 256, 0, stream>>>(Win, WinT);
    input_proj_mfma<<<NN / 32, 256, 0, stream>>>(x, ast, emb, WinT, bin_, hB);

    zero_kernel<<<(600016 / 4 + 255) / 256, 256, 0, stream>>>((float4*)rp, 600016 / 4);
    zero_kernel<<<(600000 / 4 + 255) / 256, 256, 0, stream>>>((float4*)fill, 600000 / 4);
    csr_hist<<<(3 * EE + 255) / 256, 256, 0, stream>>>(ei[0], ei[1], ei[2], rp);
    scan1<<<dim3(SCAN_NB, 3), 256, 0, stream>>>(rp, bs);
    scan2<<<3, 128, 0, stream>>>(bs);
    scan3<<<dim3(SCAN_NB, 3), 256, 0, stream>>>(rp, bs);
    csr_scatter<<<(3 * EE + 255) / 256, 256, 0, stream>>>(
        ei[0], ei[1], ei[2], rp, fill, csrc, cdst);

    for (int l = 0; l < 2; ++l) {
        const size_t ls = (size_t)l * 7;   // slots: 0=q, 1..3=kt_r, 4..6=vt_r
        gemm_mfma2<<<NN / 64, 256, 0, stream>>>(
            hB, WT + ls * 8192, bf + ls * 128, P0,
            WT + (ls + 1) * 8192, bf + (ls + 1) * 128, P1);
        edge_scores_csr<<<(EE * 4 + 255) / 256, 256, 0, stream>>>(
            P0, P1, csrc, cdst, p_rel + (size_t)l * 12, sbuf);
        for (int r = 1; r < 3; ++r) {
            gemm_mfma<<<NN / 64, 256, 0, stream>>>(
                hB, WT + (ls + 1 + r) * 8192, bf + (ls + 1 + r) * 128, P1);
            edge_scores_csr<<<(EE * 4 + 255) / 256, 256, 0, stream>>>(
                P0, P1, csrc + (size_t)r * EE, cdst + (size_t)r * EE,
                p_rel + (size_t)(l * 3 + r) * 4, sbuf + (size_t)r * EE * 4);
        }
        csr_softmax<<<NN / 4, 256, 0, stream>>>(sbuf, rp, invZ);
        gemm_mfma2<<<NN / 64, 256, 0, stream>>>(
            hB, WT + (ls + 4) * 8192, bf + (ls + 4) * 128, P0,
            WT + (ls + 5) * 8192, bf + (ls + 5) * 128, P1);
        agg_reg<2, 1><<<NN / 4, 256, 0, stream>>>(P0, P1, sbuf, rp, csrc, 0, 1, invZ, AS);
        gemm_mfma<<<NN / 64, 256, 0, stream>>>(hB, WT + (ls + 6) * 8192, bf + (ls + 6) * 128, P0);
        agg_reg<1, 0><<<NN / 4, 256, 0, stream>>>(P0, P0, sbuf, rp, csrc, 2, 2, invZ, AS);
        out_ln<<<NN / 32, 256, 0, stream>>>(
            AS, hB, WT + (size_t)(14 + l) * 8192, bout + (size_t)l * 128,
            skip + l, ln_g + (size_t)l * 128, ln_b + (size_t)l * 128);
    }

    zero_kernel<<<(16512 / 4 + 255) / 256, 256, 0, stream>>>((float4*)psum, 16512 / 4);
    pool_graph<<<BB * 8, 256, 0, stream>>>(hB, x, batch, psum, pcnt);
    head_kernel<<<BB, 256, 0, stream>>>(psum, pcnt, task, Wtf, btf, Wc1, bc1, Wc2, bc2, out);
}